// Round 1
// baseline (877.437 us; speedup 1.0000x reference)
//
#include <hip/hip_runtime.h>

#define NN 50000
#define NE 800000
#define NG 8
#define BN_EPS 1e-5f

// ---------------- degree / normalization ----------------

__global__ __launch_bounds__(256) void init_deg(float* deg) {
    int i = blockIdx.x * 256 + threadIdx.x;
    if (i < NN) deg[i] = 1.0f;  // self-loop
}

__global__ __launch_bounds__(256) void deg_edges(const int* __restrict__ dst,
                                                 float* __restrict__ deg) {
    int e = blockIdx.x * 256 + threadIdx.x;
    if (e < NE) atomicAdd(&deg[dst[e]], 1.0f);
}

__global__ __launch_bounds__(256) void finalize_dinv(float* deg) {
    int i = blockIdx.x * 256 + threadIdx.x;
    if (i < NN) deg[i] = rsqrtf(deg[i]);
}

// ---------------- dense matmul: C[N,NOUT] = A[N,CIN] @ W[CIN,NOUT] ----------------
// Register-tiled 4x4 per thread; A staged in LDS with +1 pad (conflict-free
// broadcast reads); W read through L1 as float4.

template<int CIN, int NOUT, bool BR>
__global__ __launch_bounds__(256) void matmul_kernel(
        const float* __restrict__ A, int lda,
        const float* __restrict__ W,
        const float* __restrict__ bias,
        float* __restrict__ C, int ldc) {
    constexpr int CG = NOUT / 4;      // col groups (4 cols each)
    constexpr int RG = 256 / CG;      // row groups
    constexpr int BM = RG * 4;        // rows per block
    constexpr int CINP = CIN + 1;     // LDS pad
    __shared__ float As[BM * CINP];
    const int tid = threadIdx.x;
    const int row0 = blockIdx.x * BM;

    for (int idx = tid; idx < BM * CIN; idx += 256) {
        int r = idx / CIN;
        int k = idx - r * CIN;
        int gr = row0 + r;
        As[r * CINP + k] = (gr < NN) ? A[(size_t)gr * lda + k] : 0.0f;
    }
    __syncthreads();

    const int cg = tid % CG, rg = tid / CG;
    const int c0 = cg * 4, r0 = rg * 4;
    float acc[4][4];
#pragma unroll
    for (int i = 0; i < 4; i++)
#pragma unroll
        for (int j = 0; j < 4; j++) acc[i][j] = 0.0f;

#pragma unroll 4
    for (int k = 0; k < CIN; k++) {
        const float4 wv = *reinterpret_cast<const float4*>(&W[k * NOUT + c0]);
#pragma unroll
        for (int i = 0; i < 4; i++) {
            const float a = As[(r0 + i) * CINP + k];
            acc[i][0] = fmaf(a, wv.x, acc[i][0]);
            acc[i][1] = fmaf(a, wv.y, acc[i][1]);
            acc[i][2] = fmaf(a, wv.z, acc[i][2]);
            acc[i][3] = fmaf(a, wv.w, acc[i][3]);
        }
    }

#pragma unroll
    for (int i = 0; i < 4; i++) {
        int r = row0 + r0 + i;
        if (r < NN) {
            float4 v;
            if (BR) {
                v.x = fmaxf(acc[i][0] + bias[c0 + 0], 0.0f);
                v.y = fmaxf(acc[i][1] + bias[c0 + 1], 0.0f);
                v.z = fmaxf(acc[i][2] + bias[c0 + 2], 0.0f);
                v.w = fmaxf(acc[i][3] + bias[c0 + 3], 0.0f);
            } else {
                v.x = acc[i][0]; v.y = acc[i][1]; v.z = acc[i][2]; v.w = acc[i][3];
            }
            *reinterpret_cast<float4*>(&C[(size_t)r * ldc + c0]) = v;
        }
    }
}

// ---------------- edge scatter: out[dst] += hw[src] * dinv[src]*dinv[dst] ----------------
// out points at an H column slice; H row stride is 256. Self-loops are folded
// into the post kernel analytically (hw[i]*dinv[i]^2).

__global__ __launch_bounds__(256) void scatter_edges(
        const float* __restrict__ hw, const float* __restrict__ dinv,
        const int* __restrict__ src, const int* __restrict__ dst,
        float* __restrict__ out) {
    int t = blockIdx.x * 256 + threadIdx.x;
    int e = t >> 6;
    int ch = t & 63;
    if (e < NE) {
        int s = src[e], d = dst[e];
        float coef = dinv[s] * dinv[d];
        float v = hw[s * 64 + ch] * coef;
        atomicAdd(&out[d * 256 + ch], v);
    }
}

// ---------------- self-loop + bias + BN(eval) + ReLU, in place on H slice ----------------

template<bool DUP>
__global__ __launch_bounds__(256) void post_bn_relu(
        float* __restrict__ Hs, const float* __restrict__ hw,
        const float* __restrict__ dinv,
        const float* __restrict__ b, const float* __restrict__ g,
        const float* __restrict__ beta, const float* __restrict__ rm,
        const float* __restrict__ rv) {
    int t = blockIdx.x * 256 + threadIdx.x;
    int i = t >> 6;
    int ch = t & 63;
    if (i < NN) {
        float di = dinv[i];
        float v = Hs[i * 256 + ch] + hw[i * 64 + ch] * di * di + b[ch];
        float s = g[ch] * rsqrtf(rv[ch] + BN_EPS);
        v = (v - rm[ch]) * s + beta[ch];
        v = fmaxf(v, 0.0f);
        Hs[i * 256 + ch] = v;
        if (DUP) Hs[i * 256 + 64 + ch] = v;
    }
}

// ---------------- per-graph mean pooling (stage 1: sums via predicated regs) ----------------

__global__ __launch_bounds__(256) void pool_kernel(
        const float* __restrict__ e, const int* __restrict__ batch,
        float* __restrict__ gfeat, float* __restrict__ counts) {
    const int tid = threadIdx.x;
    const int ch = tid & 63;
    const int rg = tid >> 6;  // 0..3
    float acc[NG];
    float cnt[NG];
#pragma unroll
    for (int g = 0; g < NG; g++) { acc[g] = 0.0f; cnt[g] = 0.0f; }
    for (int i = blockIdx.x * 4 + rg; i < NN; i += gridDim.x * 4) {
        int b = batch[i];
        float v = e[i * 64 + ch];
#pragma unroll
        for (int g = 0; g < NG; g++) {
            acc[g] += (b == g) ? v : 0.0f;
            cnt[g] += (b == g) ? 1.0f : 0.0f;
        }
    }
#pragma unroll
    for (int g = 0; g < NG; g++) {
        atomicAdd(&gfeat[g * 64 + ch], acc[g]);
        if (ch == 0) atomicAdd(&counts[g], cnt[g]);
    }
}

// ---------------- decoder: out[g] = relu(mean @ w0 + b0) @ w1 + b1 ----------------

__global__ __launch_bounds__(256) void dec_kernel(
        const float* __restrict__ gfeat, const float* __restrict__ counts,
        const float* __restrict__ w0, const float* __restrict__ b0,
        const float* __restrict__ w1, const float* __restrict__ b1,
        float* __restrict__ out) {
    __shared__ float t1[NG][32];
    const int tid = threadIdx.x;
    const int g = tid >> 5, c = tid & 31;
    float inv = 1.0f / fmaxf(counts[g], 1.0f);
    float acc = b0[c];
    for (int k = 0; k < 64; k++)
        acc = fmaf(gfeat[g * 64 + k] * inv, w0[k * 32 + c], acc);
    t1[g][c] = fmaxf(acc, 0.0f);
    __syncthreads();
    if (tid < NG) {
        float o = b1[0];
        for (int c2 = 0; c2 < 32; c2++) o = fmaf(t1[tid][c2], w1[c2], o);
        out[tid] = o;
    }
}

// ---------------- launch ----------------

extern "C" void kernel_launch(void* const* d_in, const int* in_sizes, int n_in,
                              void* d_out, int out_size, void* d_ws, size_t ws_size,
                              hipStream_t stream) {
    const float* x      = (const float*)d_in[0];
    const int*   ei     = (const int*)d_in[1];   // [2, NE]: src then dst
    const int*   batch  = (const int*)d_in[2];
    const float* W0     = (const float*)d_in[3];
    const float* b0     = (const float*)d_in[4];
    const float* g0     = (const float*)d_in[5];
    const float* beta0  = (const float*)d_in[6];
    const float* rm0    = (const float*)d_in[7];
    const float* rv0    = (const float*)d_in[8];
    const float* W1     = (const float*)d_in[9];
    const float* b1     = (const float*)d_in[10];
    const float* g1     = (const float*)d_in[11];
    const float* beta1  = (const float*)d_in[12];
    const float* rm1    = (const float*)d_in[13];
    const float* rv1    = (const float*)d_in[14];
    const float* W2     = (const float*)d_in[15];
    const float* b2     = (const float*)d_in[16];
    const float* g2     = (const float*)d_in[17];
    const float* beta2  = (const float*)d_in[18];
    const float* rm2    = (const float*)d_in[19];
    const float* rv2    = (const float*)d_in[20];
    const float* enc_w0 = (const float*)d_in[21];
    const float* enc_b0 = (const float*)d_in[22];
    const float* enc_w1 = (const float*)d_in[23];
    const float* enc_b1 = (const float*)d_in[24];
    const float* dec_w0 = (const float*)d_in[25];
    const float* dec_b0 = (const float*)d_in[26];
    const float* dec_w1 = (const float*)d_in[27];
    const float* dec_b1 = (const float*)d_in[28];

    const int* esrc = ei;
    const int* edst = ei + NE;

    float* ws = (float*)d_ws;
    float* H      = ws;                           // [NN,256] = [c0 | c0 | c1 | c2]
    float* T      = H + (size_t)NN * 256;         // [NN,128] enc hidden
    float* hw     = T + (size_t)NN * 128;         // [NN,64]  matmul out / e
    float* dinv   = hw + (size_t)NN * 64;         // [NN]
    float* gfeat  = dinv + NN;                    // [8*64]
    float* counts = gfeat + NG * 64;              // [8]

    // zero aggregation targets + pooling accumulators
    hipMemsetAsync(H, 0, (size_t)NN * 256 * sizeof(float), stream);
    hipMemsetAsync(gfeat, 0, (NG * 64 + NG) * sizeof(float), stream);

    // degree -> dinv (self-loop included via init to 1)
    init_deg<<<(NN + 255) / 256, 256, 0, stream>>>(dinv);
    deg_edges<<<(NE + 255) / 256, 256, 0, stream>>>(edst, dinv);
    finalize_dinv<<<(NN + 255) / 256, 256, 0, stream>>>(dinv);

    const int GRID_MM64  = (NN + 63) / 64;    // NOUT=64 -> BM=64
    const int GRID_MM128 = (NN + 31) / 32;    // NOUT=128 -> BM=32
    const int GRID_SC    = (NE * 64) / 256;
    const int GRID_POST  = (NN * 64 + 255) / 256;

    // ---- layer 0: x[N,3] -> c0 (cols 0-63, dup to 64-127) ----
    matmul_kernel<3, 64, false><<<GRID_MM64, 256, 0, stream>>>(x, 3, W0, nullptr, hw, 64);
    scatter_edges<<<GRID_SC, 256, 0, stream>>>(hw, dinv, esrc, edst, H + 0);
    post_bn_relu<true><<<GRID_POST, 256, 0, stream>>>(H + 0, hw, dinv, b0, g0, beta0, rm0, rv0);

    // ---- layer 1: h0 (H+0, 64) -> c1 (cols 128-191) ----
    matmul_kernel<64, 64, false><<<GRID_MM64, 256, 0, stream>>>(H, 256, W1, nullptr, hw, 64);
    scatter_edges<<<GRID_SC, 256, 0, stream>>>(hw, dinv, esrc, edst, H + 128);
    post_bn_relu<false><<<GRID_POST, 256, 0, stream>>>(H + 128, hw, dinv, b1, g1, beta1, rm1, rv1);

    // ---- layer 2: h1cat (H+64, 128) -> c2 (cols 192-255) ----
    matmul_kernel<128, 64, false><<<GRID_MM64, 256, 0, stream>>>(H + 64, 256, W2, nullptr, hw, 64);
    scatter_edges<<<GRID_SC, 256, 0, stream>>>(hw, dinv, esrc, edst, H + 192);
    post_bn_relu<false><<<GRID_POST, 256, 0, stream>>>(H + 192, hw, dinv, b2, g2, beta2, rm2, rv2);

    // ---- encoder ----
    matmul_kernel<256, 128, true><<<GRID_MM128, 256, 0, stream>>>(H, 256, enc_w0, enc_b0, T, 128);
    matmul_kernel<128, 64, true><<<GRID_MM64, 256, 0, stream>>>(T, 128, enc_w1, enc_b1, hw, 64);

    // ---- pool + decode ----
    pool_kernel<<<64, 256, 0, stream>>>(hw, batch, gfeat, counts);
    dec_kernel<<<1, 256, 0, stream>>>(gfeat, counts, dec_w0, dec_b0, dec_w1, dec_b1, (float*)d_out);
}

// Round 2
// 629.812 us; speedup vs baseline: 1.3932x; 1.3932x over previous
//
#include <hip/hip_runtime.h>

#define NN 50000
#define NE 800000
#define NG 8
#define BN_EPS 1e-5f

// ---------------- CSR build ----------------

__global__ __launch_bounds__(256) void count_deg(const int* __restrict__ dst,
                                                 int* __restrict__ degi) {
    int e = blockIdx.x * 256 + threadIdx.x;
    if (e < NE) atomicAdd(&degi[dst[e]], 1);
}

__global__ __launch_bounds__(256) void compute_dinv(const int* __restrict__ degi,
                                                    float* __restrict__ dinv) {
    int i = blockIdx.x * 256 + threadIdx.x;
    if (i < NN) dinv[i] = rsqrtf((float)(degi[i] + 1));  // +1 self-loop
}

// single-block scan: rowptr (exclusive) + cursor init
__global__ __launch_bounds__(1024) void scan_kernel(const int* __restrict__ degi,
                                                    int* __restrict__ rowptr,
                                                    int* __restrict__ cursor) {
    __shared__ int part[1024];
    const int tid = threadIdx.x;
    const int SEG = (NN + 1023) / 1024;  // 49
    const int s0 = tid * SEG;
    int sum = 0;
    for (int k = 0; k < SEG; k++) {
        int i = s0 + k;
        if (i < NN) sum += degi[i];
    }
    part[tid] = sum;
    __syncthreads();
    for (int off = 1; off < 1024; off <<= 1) {
        int v = (tid >= off) ? part[tid - off] : 0;
        __syncthreads();
        part[tid] += v;
        __syncthreads();
    }
    int base = (tid == 0) ? 0 : part[tid - 1];
    for (int k = 0; k < SEG; k++) {
        int i = s0 + k;
        if (i < NN) {
            rowptr[i] = base;
            cursor[i] = base;
            base += degi[i];
        }
    }
    if (tid == 1023) rowptr[NN] = base;
}

__global__ __launch_bounds__(256) void fill_csr(const int* __restrict__ src,
                                                const int* __restrict__ dst,
                                                const float* __restrict__ dinv,
                                                int* __restrict__ cursor,
                                                int* __restrict__ esrc_s,
                                                float* __restrict__ ecoef_s) {
    int e = blockIdx.x * 256 + threadIdx.x;
    if (e < NE) {
        int s = src[e], d = dst[e];
        int p = atomicAdd(&cursor[d], 1);
        esrc_s[p] = s;
        ecoef_s[p] = dinv[s] * dinv[d];
    }
}

// ---------------- dense matmul: C[N,NOUT] = A[N,CIN] @ W[CIN,NOUT] ----------------

template<int CIN, int NOUT, bool BR>
__global__ __launch_bounds__(256) void matmul_kernel(
        const float* __restrict__ A, int lda,
        const float* __restrict__ W,
        const float* __restrict__ bias,
        float* __restrict__ C, int ldc) {
    constexpr int CG = NOUT / 4;
    constexpr int RG = 256 / CG;
    constexpr int BM = RG * 4;
    constexpr int CINP = CIN + 1;
    __shared__ float As[BM * CINP];
    const int tid = threadIdx.x;
    const int row0 = blockIdx.x * BM;

    for (int idx = tid; idx < BM * CIN; idx += 256) {
        int r = idx / CIN;
        int k = idx - r * CIN;
        int gr = row0 + r;
        As[r * CINP + k] = (gr < NN) ? A[(size_t)gr * lda + k] : 0.0f;
    }
    __syncthreads();

    const int cg = tid % CG, rg = tid / CG;
    const int c0 = cg * 4, r0 = rg * 4;
    float acc[4][4];
#pragma unroll
    for (int i = 0; i < 4; i++)
#pragma unroll
        for (int j = 0; j < 4; j++) acc[i][j] = 0.0f;

#pragma unroll 4
    for (int k = 0; k < CIN; k++) {
        const float4 wv = *reinterpret_cast<const float4*>(&W[k * NOUT + c0]);
#pragma unroll
        for (int i = 0; i < 4; i++) {
            const float a = As[(r0 + i) * CINP + k];
            acc[i][0] = fmaf(a, wv.x, acc[i][0]);
            acc[i][1] = fmaf(a, wv.y, acc[i][1]);
            acc[i][2] = fmaf(a, wv.z, acc[i][2]);
            acc[i][3] = fmaf(a, wv.w, acc[i][3]);
        }
    }

#pragma unroll
    for (int i = 0; i < 4; i++) {
        int r = row0 + r0 + i;
        if (r < NN) {
            float4 v;
            if (BR) {
                v.x = fmaxf(acc[i][0] + bias[c0 + 0], 0.0f);
                v.y = fmaxf(acc[i][1] + bias[c0 + 1], 0.0f);
                v.z = fmaxf(acc[i][2] + bias[c0 + 2], 0.0f);
                v.w = fmaxf(acc[i][3] + bias[c0 + 3], 0.0f);
            } else {
                v.x = acc[i][0]; v.y = acc[i][1]; v.z = acc[i][2]; v.w = acc[i][3];
            }
            *reinterpret_cast<float4*>(&C[(size_t)r * ldc + c0]) = v;
        }
    }
}

// ---------------- fused gather + self-loop + bias + BN + ReLU + concat-write ----------------
// One wave (64 lanes = 64 channels) per destination node.

template<bool DUP>
__global__ __launch_bounds__(256) void gather_bn_relu(
        const float* __restrict__ hw,
        const int* __restrict__ rowptr,
        const int* __restrict__ esrc,
        const float* __restrict__ ecoef,
        const float* __restrict__ dinv,
        const float* __restrict__ b, const float* __restrict__ g,
        const float* __restrict__ beta, const float* __restrict__ rm,
        const float* __restrict__ rv,
        float* __restrict__ Hs) {
    const int wid = (blockIdx.x * 256 + threadIdx.x) >> 6;  // node id
    const int ch = threadIdx.x & 63;
    if (wid >= NN) return;
    const int beg = rowptr[wid], end = rowptr[wid + 1];
    const float di = dinv[wid];
    float acc = hw[wid * 64 + ch] * di * di;  // self-loop
    int e = beg;
    for (; e + 1 < end; e += 2) {
        int s0 = esrc[e], s1 = esrc[e + 1];
        float c0 = ecoef[e], c1 = ecoef[e + 1];
        acc = fmaf(hw[s0 * 64 + ch], c0, acc);
        acc = fmaf(hw[s1 * 64 + ch], c1, acc);
    }
    if (e < end) {
        acc = fmaf(hw[esrc[e] * 64 + ch], ecoef[e], acc);
    }
    float sc = g[ch] * rsqrtf(rv[ch] + BN_EPS);
    float v = (acc + b[ch] - rm[ch]) * sc + beta[ch];
    v = fmaxf(v, 0.0f);
    Hs[wid * 256 + ch] = v;
    if (DUP) Hs[wid * 256 + 64 + ch] = v;
}

// ---------------- per-graph mean pooling ----------------

__global__ __launch_bounds__(256) void pool_kernel(
        const float* __restrict__ e, const int* __restrict__ batch,
        float* __restrict__ gfeat, float* __restrict__ counts) {
    const int tid = threadIdx.x;
    const int ch = tid & 63;
    const int rg = tid >> 6;
    float acc[NG];
    float cnt[NG];
#pragma unroll
    for (int g = 0; g < NG; g++) { acc[g] = 0.0f; cnt[g] = 0.0f; }
    for (int i = blockIdx.x * 4 + rg; i < NN; i += gridDim.x * 4) {
        int b = batch[i];
        float v = e[i * 64 + ch];
#pragma unroll
        for (int g = 0; g < NG; g++) {
            acc[g] += (b == g) ? v : 0.0f;
            cnt[g] += (b == g) ? 1.0f : 0.0f;
        }
    }
#pragma unroll
    for (int g = 0; g < NG; g++) {
        atomicAdd(&gfeat[g * 64 + ch], acc[g]);
        if (ch == 0) atomicAdd(&counts[g], cnt[g]);
    }
}

// ---------------- decoder ----------------

__global__ __launch_bounds__(256) void dec_kernel(
        const float* __restrict__ gfeat, const float* __restrict__ counts,
        const float* __restrict__ w0, const float* __restrict__ b0,
        const float* __restrict__ w1, const float* __restrict__ b1,
        float* __restrict__ out) {
    __shared__ float t1[NG][32];
    const int tid = threadIdx.x;
    const int g = tid >> 5, c = tid & 31;
    float inv = 1.0f / fmaxf(counts[g], 1.0f);
    float acc = b0[c];
    for (int k = 0; k < 64; k++)
        acc = fmaf(gfeat[g * 64 + k] * inv, w0[k * 32 + c], acc);
    t1[g][c] = fmaxf(acc, 0.0f);
    __syncthreads();
    if (tid < NG) {
        float o = b1[0];
        for (int c2 = 0; c2 < 32; c2++) o = fmaf(t1[tid][c2], w1[c2], o);
        out[tid] = o;
    }
}

// ---------------- launch ----------------

extern "C" void kernel_launch(void* const* d_in, const int* in_sizes, int n_in,
                              void* d_out, int out_size, void* d_ws, size_t ws_size,
                              hipStream_t stream) {
    const float* x      = (const float*)d_in[0];
    const int*   ei     = (const int*)d_in[1];
    const int*   batch  = (const int*)d_in[2];
    const float* W0     = (const float*)d_in[3];
    const float* b0     = (const float*)d_in[4];
    const float* g0     = (const float*)d_in[5];
    const float* beta0  = (const float*)d_in[6];
    const float* rm0    = (const float*)d_in[7];
    const float* rv0    = (const float*)d_in[8];
    const float* W1     = (const float*)d_in[9];
    const float* b1     = (const float*)d_in[10];
    const float* g1     = (const float*)d_in[11];
    const float* beta1  = (const float*)d_in[12];
    const float* rm1    = (const float*)d_in[13];
    const float* rv1    = (const float*)d_in[14];
    const float* W2     = (const float*)d_in[15];
    const float* b2     = (const float*)d_in[16];
    const float* g2     = (const float*)d_in[17];
    const float* beta2  = (const float*)d_in[18];
    const float* rm2    = (const float*)d_in[19];
    const float* rv2    = (const float*)d_in[20];
    const float* enc_w0 = (const float*)d_in[21];
    const float* enc_b0 = (const float*)d_in[22];
    const float* enc_w1 = (const float*)d_in[23];
    const float* enc_b1 = (const float*)d_in[24];
    const float* dec_w0 = (const float*)d_in[25];
    const float* dec_b0 = (const float*)d_in[26];
    const float* dec_w1 = (const float*)d_in[27];
    const float* dec_b1 = (const float*)d_in[28];

    const int* esrc = ei;
    const int* edst = ei + NE;

    // workspace layout (floats); U region is aliased: CSR arrays live there
    // until the last gather, then enc-hidden T reuses it.
    float* ws = (float*)d_ws;
    float* H      = ws;                            // [NN,256] = [c0|c0|c1|c2]
    float* U      = H + (size_t)NN * 256;          // union region
    float* T      = U;                             // [NN,128] enc hidden
    int*   degi   = (int*)U;                       // [NN]
    int*   rowptr = degi + NN;                     // [NN+1]
    int*   cursor = rowptr + NN + 1;               // [NN]
    int*   esrc_s = cursor + NN;                   // [NE]
    float* ecoef_s= (float*)(esrc_s + NE);         // [NE]
    float* hw     = U + (size_t)NN * 128;          // [NN,64]
    float* dinv   = hw + (size_t)NN * 64;          // [NN]
    float* gfeat  = dinv + NN;                     // [8*64]
    float* counts = gfeat + NG * 64;               // [8]

    hipMemsetAsync(gfeat, 0, (NG * 64 + NG) * sizeof(float), stream);
    hipMemsetAsync(degi, 0, NN * sizeof(int), stream);

    // CSR build
    count_deg<<<(NE + 255) / 256, 256, 0, stream>>>(edst, degi);
    compute_dinv<<<(NN + 255) / 256, 256, 0, stream>>>(degi, dinv);
    scan_kernel<<<1, 1024, 0, stream>>>(degi, rowptr, cursor);
    fill_csr<<<(NE + 255) / 256, 256, 0, stream>>>(esrc, edst, dinv, cursor, esrc_s, ecoef_s);

    const int GRID_MM64  = (NN + 63) / 64;
    const int GRID_MM128 = (NN + 31) / 32;
    const int GRID_GATH  = (NN * 64 + 255) / 256;  // one wave per node

    // ---- layer 0: x[N,3] -> c0 (cols 0-63, dup 64-127) ----
    matmul_kernel<3, 64, false><<<GRID_MM64, 256, 0, stream>>>(x, 3, W0, nullptr, hw, 64);
    gather_bn_relu<true><<<GRID_GATH, 256, 0, stream>>>(hw, rowptr, esrc_s, ecoef_s, dinv,
                                                        b0, g0, beta0, rm0, rv0, H + 0);

    // ---- layer 1: h0 (H+0, 64) -> c1 (cols 128-191) ----
    matmul_kernel<64, 64, false><<<GRID_MM64, 256, 0, stream>>>(H, 256, W1, nullptr, hw, 64);
    gather_bn_relu<false><<<GRID_GATH, 256, 0, stream>>>(hw, rowptr, esrc_s, ecoef_s, dinv,
                                                         b1, g1, beta1, rm1, rv1, H + 128);

    // ---- layer 2: h1cat (H+64, 128) -> c2 (cols 192-255) ----
    matmul_kernel<128, 64, false><<<GRID_MM64, 256, 0, stream>>>(H + 64, 256, W2, nullptr, hw, 64);
    gather_bn_relu<false><<<GRID_GATH, 256, 0, stream>>>(hw, rowptr, esrc_s, ecoef_s, dinv,
                                                         b2, g2, beta2, rm2, rv2, H + 192);

    // ---- encoder (T overwrites CSR region; CSR dead from here) ----
    matmul_kernel<256, 128, true><<<GRID_MM128, 256, 0, stream>>>(H, 256, enc_w0, enc_b0, T, 128);
    matmul_kernel<128, 64, true><<<GRID_MM64, 256, 0, stream>>>(T, 128, enc_w1, enc_b1, hw, 64);

    // ---- pool + decode ----
    pool_kernel<<<64, 256, 0, stream>>>(hw, batch, gfeat, counts);
    dec_kernel<<<1, 256, 0, stream>>>(gfeat, counts, dec_w0, dec_b0, dec_w1, dec_b1, (float*)d_out);
}

// Round 3
// 531.443 us; speedup vs baseline: 1.6510x; 1.1851x over previous
//
#include <hip/hip_runtime.h>

#define NN 50000
#define NE 800000
#define NG 8
#define BN_EPS 1e-5f
#define NBLK ((NN + 255) / 256)   // 196 scan blocks

// ---------------- CSR build ----------------

__global__ __launch_bounds__(256) void count_deg(const int* __restrict__ dst,
                                                 int* __restrict__ degi) {
    int e = blockIdx.x * 256 + threadIdx.x;
    if (e < NE) atomicAdd(&degi[dst[e]], 1);
}

__global__ __launch_bounds__(256) void compute_dinv(const int* __restrict__ degi,
                                                    float* __restrict__ dinv) {
    int i = blockIdx.x * 256 + threadIdx.x;
    if (i < NN) dinv[i] = rsqrtf((float)(degi[i] + 1));  // +1 self-loop
}

// hierarchical scan stage 1: per-block exclusive scan + block sums
__global__ __launch_bounds__(256) void scan_partial(const int* __restrict__ degi,
                                                    int* __restrict__ rowptr,
                                                    int* __restrict__ bsum) {
    __shared__ int sh[256];
    const int tid = threadIdx.x;
    const int i = blockIdx.x * 256 + tid;
    int v = (i < NN) ? degi[i] : 0;
    sh[tid] = v;
    __syncthreads();
#pragma unroll
    for (int off = 1; off < 256; off <<= 1) {
        int t = (tid >= off) ? sh[tid - off] : 0;
        __syncthreads();
        sh[tid] += t;
        __syncthreads();
    }
    if (i < NN) rowptr[i] = sh[tid] - v;  // block-local exclusive
    if (tid == 255) bsum[blockIdx.x] = sh[255];
}

// stage 2: exclusive scan of the 196 block sums (single small block)
__global__ __launch_bounds__(256) void scan_bsums(int* __restrict__ bsum) {
    __shared__ int sh[256];
    const int tid = threadIdx.x;
    int v = (tid < NBLK) ? bsum[tid] : 0;
    sh[tid] = v;
    __syncthreads();
#pragma unroll
    for (int off = 1; off < 256; off <<= 1) {
        int t = (tid >= off) ? sh[tid - off] : 0;
        __syncthreads();
        sh[tid] += t;
        __syncthreads();
    }
    if (tid < NBLK) bsum[tid] = sh[tid] - v;  // exclusive block base
}

// stage 3: add block bases, init cursor, pin rowptr[NN]=NE
__global__ __launch_bounds__(256) void scan_finalize(const int* __restrict__ bsum,
                                                     int* __restrict__ rowptr,
                                                     int* __restrict__ cursor) {
    const int i = blockIdx.x * 256 + threadIdx.x;
    if (i < NN) {
        int r = rowptr[i] + bsum[blockIdx.x];
        rowptr[i] = r;
        cursor[i] = r;
    }
    if (i == 0) rowptr[NN] = NE;
}

__global__ __launch_bounds__(256) void fill_csr(const int* __restrict__ src,
                                                const int* __restrict__ dst,
                                                const float* __restrict__ dinv,
                                                int* __restrict__ cursor,
                                                int* __restrict__ esrc_s,
                                                float* __restrict__ ecoef_s) {
    int e = blockIdx.x * 256 + threadIdx.x;
    if (e < NE) {
        int s = src[e], d = dst[e];
        int p = atomicAdd(&cursor[d], 1);
        esrc_s[p] = s;
        ecoef_s[p] = dinv[s] * dinv[d];
    }
}

// ---------------- dense matmul: C[N,NOUT] = A[N,CIN] @ W[CIN,NOUT] ----------------

template<int CIN, int NOUT, bool BR>
__global__ __launch_bounds__(256) void matmul_kernel(
        const float* __restrict__ A, int lda,
        const float* __restrict__ W,
        const float* __restrict__ bias,
        float* __restrict__ C, int ldc) {
    constexpr int CG = NOUT / 4;
    constexpr int RG = 256 / CG;
    constexpr int BM = RG * 4;
    constexpr int CINP = CIN + 1;
    __shared__ float As[BM * CINP];
    const int tid = threadIdx.x;
    const int row0 = blockIdx.x * BM;

    for (int idx = tid; idx < BM * CIN; idx += 256) {
        int r = idx / CIN;
        int k = idx - r * CIN;
        int gr = row0 + r;
        As[r * CINP + k] = (gr < NN) ? A[(size_t)gr * lda + k] : 0.0f;
    }
    __syncthreads();

    const int cg = tid % CG, rg = tid / CG;
    const int c0 = cg * 4, r0 = rg * 4;
    float acc[4][4];
#pragma unroll
    for (int i = 0; i < 4; i++)
#pragma unroll
        for (int j = 0; j < 4; j++) acc[i][j] = 0.0f;

#pragma unroll 4
    for (int k = 0; k < CIN; k++) {
        const float4 wv = *reinterpret_cast<const float4*>(&W[k * NOUT + c0]);
#pragma unroll
        for (int i = 0; i < 4; i++) {
            const float a = As[(r0 + i) * CINP + k];
            acc[i][0] = fmaf(a, wv.x, acc[i][0]);
            acc[i][1] = fmaf(a, wv.y, acc[i][1]);
            acc[i][2] = fmaf(a, wv.z, acc[i][2]);
            acc[i][3] = fmaf(a, wv.w, acc[i][3]);
        }
    }

#pragma unroll
    for (int i = 0; i < 4; i++) {
        int r = row0 + r0 + i;
        if (r < NN) {
            float4 v;
            if (BR) {
                v.x = fmaxf(acc[i][0] + bias[c0 + 0], 0.0f);
                v.y = fmaxf(acc[i][1] + bias[c0 + 1], 0.0f);
                v.z = fmaxf(acc[i][2] + bias[c0 + 2], 0.0f);
                v.w = fmaxf(acc[i][3] + bias[c0 + 3], 0.0f);
            } else {
                v.x = acc[i][0]; v.y = acc[i][1]; v.z = acc[i][2]; v.w = acc[i][3];
            }
            *reinterpret_cast<float4*>(&C[(size_t)r * ldc + c0]) = v;
        }
    }
}

// ---------------- fused gather + self-loop + bias + BN + ReLU + concat-write ----------------

template<bool DUP>
__global__ __launch_bounds__(256) void gather_bn_relu(
        const float* __restrict__ hw,
        const int* __restrict__ rowptr,
        const int* __restrict__ esrc,
        const float* __restrict__ ecoef,
        const float* __restrict__ dinv,
        const float* __restrict__ b, const float* __restrict__ g,
        const float* __restrict__ beta, const float* __restrict__ rm,
        const float* __restrict__ rv,
        float* __restrict__ Hs) {
    const int wid = (blockIdx.x * 256 + threadIdx.x) >> 6;  // node id
    const int ch = threadIdx.x & 63;
    if (wid >= NN) return;
    const int beg = rowptr[wid], end = rowptr[wid + 1];
    const float di = dinv[wid];
    float acc = hw[wid * 64 + ch] * di * di;  // self-loop
    int e = beg;
    for (; e + 1 < end; e += 2) {
        int s0 = esrc[e], s1 = esrc[e + 1];
        float c0 = ecoef[e], c1 = ecoef[e + 1];
        acc = fmaf(hw[s0 * 64 + ch], c0, acc);
        acc = fmaf(hw[s1 * 64 + ch], c1, acc);
    }
    if (e < end) {
        acc = fmaf(hw[esrc[e] * 64 + ch], ecoef[e], acc);
    }
    float sc = g[ch] * rsqrtf(rv[ch] + BN_EPS);
    float v = (acc + b[ch] - rm[ch]) * sc + beta[ch];
    v = fmaxf(v, 0.0f);
    Hs[wid * 256 + ch] = v;
    if (DUP) Hs[wid * 256 + 64 + ch] = v;
}

// ---------------- per-graph mean pooling ----------------

__global__ __launch_bounds__(256) void pool_kernel(
        const float* __restrict__ e, const int* __restrict__ batch,
        float* __restrict__ gfeat, float* __restrict__ counts) {
    const int tid = threadIdx.x;
    const int ch = tid & 63;
    const int rg = tid >> 6;
    float acc[NG];
    float cnt[NG];
#pragma unroll
    for (int g = 0; g < NG; g++) { acc[g] = 0.0f; cnt[g] = 0.0f; }
    for (int i = blockIdx.x * 4 + rg; i < NN; i += gridDim.x * 4) {
        int b = batch[i];
        float v = e[i * 64 + ch];
#pragma unroll
        for (int g = 0; g < NG; g++) {
            acc[g] += (b == g) ? v : 0.0f;
            cnt[g] += (b == g) ? 1.0f : 0.0f;
        }
    }
#pragma unroll
    for (int g = 0; g < NG; g++) {
        atomicAdd(&gfeat[g * 64 + ch], acc[g]);
        if (ch == 0) atomicAdd(&counts[g], cnt[g]);
    }
}

// ---------------- decoder ----------------

__global__ __launch_bounds__(256) void dec_kernel(
        const float* __restrict__ gfeat, const float* __restrict__ counts,
        const float* __restrict__ w0, const float* __restrict__ b0,
        const float* __restrict__ w1, const float* __restrict__ b1,
        float* __restrict__ out) {
    __shared__ float t1[NG][32];
    const int tid = threadIdx.x;
    const int g = tid >> 5, c = tid & 31;
    float inv = 1.0f / fmaxf(counts[g], 1.0f);
    float acc = b0[c];
    for (int k = 0; k < 64; k++)
        acc = fmaf(gfeat[g * 64 + k] * inv, w0[k * 32 + c], acc);
    t1[g][c] = fmaxf(acc, 0.0f);
    __syncthreads();
    if (tid < NG) {
        float o = b1[0];
        for (int c2 = 0; c2 < 32; c2++) o = fmaf(t1[tid][c2], w1[c2], o);
        out[tid] = o;
    }
}

// ---------------- launch ----------------

extern "C" void kernel_launch(void* const* d_in, const int* in_sizes, int n_in,
                              void* d_out, int out_size, void* d_ws, size_t ws_size,
                              hipStream_t stream) {
    const float* x      = (const float*)d_in[0];
    const int*   ei     = (const int*)d_in[1];
    const int*   batch  = (const int*)d_in[2];
    const float* W0     = (const float*)d_in[3];
    const float* b0     = (const float*)d_in[4];
    const float* g0     = (const float*)d_in[5];
    const float* beta0  = (const float*)d_in[6];
    const float* rm0    = (const float*)d_in[7];
    const float* rv0    = (const float*)d_in[8];
    const float* W1     = (const float*)d_in[9];
    const float* b1     = (const float*)d_in[10];
    const float* g1     = (const float*)d_in[11];
    const float* beta1  = (const float*)d_in[12];
    const float* rm1    = (const float*)d_in[13];
    const float* rv1    = (const float*)d_in[14];
    const float* W2     = (const float*)d_in[15];
    const float* b2     = (const float*)d_in[16];
    const float* g2     = (const float*)d_in[17];
    const float* beta2  = (const float*)d_in[18];
    const float* rm2    = (const float*)d_in[19];
    const float* rv2    = (const float*)d_in[20];
    const float* enc_w0 = (const float*)d_in[21];
    const float* enc_b0 = (const float*)d_in[22];
    const float* enc_w1 = (const float*)d_in[23];
    const float* enc_b1 = (const float*)d_in[24];
    const float* dec_w0 = (const float*)d_in[25];
    const float* dec_b0 = (const float*)d_in[26];
    const float* dec_w1 = (const float*)d_in[27];
    const float* dec_b1 = (const float*)d_in[28];

    const int* esrc = ei;
    const int* edst = ei + NE;

    // workspace layout (floats); U region aliased: CSR lives there until the
    // last gather, then enc-hidden T reuses it.
    float* ws = (float*)d_ws;
    float* H      = ws;                            // [NN,256] = [c0|c0|c1|c2]
    float* U      = H + (size_t)NN * 256;          // union region
    float* T      = U;                             // [NN,128] enc hidden
    int*   degi   = (int*)U;                       // [NN]
    int*   rowptr = degi + NN;                     // [NN+1]
    int*   cursor = rowptr + NN + 1;               // [NN]
    int*   esrc_s = cursor + NN;                   // [NE]
    float* ecoef_s= (float*)(esrc_s + NE);         // [NE]
    float* hw     = U + (size_t)NN * 128;          // [NN,64]
    float* dinv   = hw + (size_t)NN * 64;          // [NN]
    float* gfeat  = dinv + NN;                     // [8*64]
    float* counts = gfeat + NG * 64;               // [8]
    int*   bsum   = (int*)(counts + NG);           // [NBLK]

    hipMemsetAsync(gfeat, 0, (NG * 64 + NG) * sizeof(float), stream);
    hipMemsetAsync(degi, 0, NN * sizeof(int), stream);

    // CSR build (hierarchical scan: 3 tiny kernels instead of 1-block scan)
    count_deg<<<(NE + 255) / 256, 256, 0, stream>>>(edst, degi);
    compute_dinv<<<NBLK, 256, 0, stream>>>(degi, dinv);
    scan_partial<<<NBLK, 256, 0, stream>>>(degi, rowptr, bsum);
    scan_bsums<<<1, 256, 0, stream>>>(bsum);
    scan_finalize<<<NBLK, 256, 0, stream>>>(bsum, rowptr, cursor);
    fill_csr<<<(NE + 255) / 256, 256, 0, stream>>>(esrc, edst, dinv, cursor, esrc_s, ecoef_s);

    const int GRID_MM64  = (NN + 63) / 64;
    const int GRID_MM128 = (NN + 31) / 32;
    const int GRID_GATH  = (NN * 64 + 255) / 256;

    // ---- layer 0: x[N,3] -> c0 (cols 0-63, dup 64-127) ----
    matmul_kernel<3, 64, false><<<GRID_MM64, 256, 0, stream>>>(x, 3, W0, nullptr, hw, 64);
    gather_bn_relu<true><<<GRID_GATH, 256, 0, stream>>>(hw, rowptr, esrc_s, ecoef_s, dinv,
                                                        b0, g0, beta0, rm0, rv0, H + 0);

    // ---- layer 1: h0 (H+0, 64) -> c1 (cols 128-191) ----
    matmul_kernel<64, 64, false><<<GRID_MM64, 256, 0, stream>>>(H, 256, W1, nullptr, hw, 64);
    gather_bn_relu<false><<<GRID_GATH, 256, 0, stream>>>(hw, rowptr, esrc_s, ecoef_s, dinv,
                                                         b1, g1, beta1, rm1, rv1, H + 128);

    // ---- layer 2: h1cat (H+64, 128) -> c2 (cols 192-255) ----
    matmul_kernel<128, 64, false><<<GRID_MM64, 256, 0, stream>>>(H + 64, 256, W2, nullptr, hw, 64);
    gather_bn_relu<false><<<GRID_GATH, 256, 0, stream>>>(hw, rowptr, esrc_s, ecoef_s, dinv,
                                                         b2, g2, beta2, rm2, rv2, H + 192);

    // ---- encoder (T overwrites CSR region; CSR dead from here) ----
    matmul_kernel<256, 128, true><<<GRID_MM128, 256, 0, stream>>>(H, 256, enc_w0, enc_b0, T, 128);
    matmul_kernel<128, 64, true><<<GRID_MM64, 256, 0, stream>>>(T, 128, enc_w1, enc_b1, hw, 64);

    // ---- pool + decode ----
    pool_kernel<<<64, 256, 0, stream>>>(hw, batch, gfeat, counts);
    dec_kernel<<<1, 256, 0, stream>>>(gfeat, counts, dec_w0, dec_b0, dec_w1, dec_b1, (float*)d_out);
}

// Round 4
// 433.315 us; speedup vs baseline: 2.0249x; 1.2265x over previous
//
#include <hip/hip_runtime.h>

#define NN 50000
#define NE 800000
#define NG 8
#define BN_EPS 1e-5f
#define NBLK ((NN + 255) / 256)   // 196 scan blocks
#define POOL_BLOCKS 512
#define NPART 8

// ---------------- CSR build ----------------

__global__ __launch_bounds__(256) void count_deg(const int* __restrict__ dst,
                                                 int* __restrict__ degi) {
    int e = blockIdx.x * 256 + threadIdx.x;
    if (e < NE) atomicAdd(&degi[dst[e]], 1);
}

__global__ __launch_bounds__(256) void compute_dinv(const int* __restrict__ degi,
                                                    float* __restrict__ dinv) {
    int i = blockIdx.x * 256 + threadIdx.x;
    if (i < NN) dinv[i] = rsqrtf((float)(degi[i] + 1));  // +1 self-loop
}

// hierarchical scan stage 1: per-block exclusive scan + block sums
__global__ __launch_bounds__(256) void scan_partial(const int* __restrict__ degi,
                                                    int* __restrict__ rowptr,
                                                    int* __restrict__ bsum) {
    __shared__ int sh[256];
    const int tid = threadIdx.x;
    const int i = blockIdx.x * 256 + tid;
    int v = (i < NN) ? degi[i] : 0;
    sh[tid] = v;
    __syncthreads();
#pragma unroll
    for (int off = 1; off < 256; off <<= 1) {
        int t = (tid >= off) ? sh[tid - off] : 0;
        __syncthreads();
        sh[tid] += t;
        __syncthreads();
    }
    if (i < NN) rowptr[i] = sh[tid] - v;  // block-local exclusive
    if (tid == 255) bsum[blockIdx.x] = sh[255];
}

// stage 2: exclusive scan of the 196 block sums
__global__ __launch_bounds__(256) void scan_bsums(int* __restrict__ bsum) {
    __shared__ int sh[256];
    const int tid = threadIdx.x;
    int v = (tid < NBLK) ? bsum[tid] : 0;
    sh[tid] = v;
    __syncthreads();
#pragma unroll
    for (int off = 1; off < 256; off <<= 1) {
        int t = (tid >= off) ? sh[tid - off] : 0;
        __syncthreads();
        sh[tid] += t;
        __syncthreads();
    }
    if (tid < NBLK) bsum[tid] = sh[tid] - v;  // exclusive block base
}

// stage 3: add block bases, init cursor, pin rowptr[NN]=NE
__global__ __launch_bounds__(256) void scan_finalize(const int* __restrict__ bsum,
                                                     int* __restrict__ rowptr,
                                                     int* __restrict__ cursor) {
    const int i = blockIdx.x * 256 + threadIdx.x;
    if (i < NN) {
        int r = rowptr[i] + bsum[blockIdx.x];
        rowptr[i] = r;
        cursor[i] = r;
    }
    if (i == 0) rowptr[NN] = NE;
}

__global__ __launch_bounds__(256) void fill_csr(const int* __restrict__ src,
                                                const int* __restrict__ dst,
                                                const float* __restrict__ dinv,
                                                int* __restrict__ cursor,
                                                int* __restrict__ esrc_s,
                                                float* __restrict__ ecoef_s) {
    int e = blockIdx.x * 256 + threadIdx.x;
    if (e < NE) {
        int s = src[e], d = dst[e];
        int p = atomicAdd(&cursor[d], 1);
        esrc_s[p] = s;
        ecoef_s[p] = dinv[s] * dinv[d];
    }
}

// ---------------- dense matmul: C[N,NOUT] = A[N,CIN] @ W[CIN,NOUT] ----------------

template<int CIN, int NOUT, bool BR>
__global__ __launch_bounds__(256) void matmul_kernel(
        const float* __restrict__ A, int lda,
        const float* __restrict__ W,
        const float* __restrict__ bias,
        float* __restrict__ C, int ldc) {
    constexpr int CG = NOUT / 4;
    constexpr int RG = 256 / CG;
    constexpr int BM = RG * 4;
    constexpr int CINP = CIN + 1;
    __shared__ float As[BM * CINP];
    const int tid = threadIdx.x;
    const int row0 = blockIdx.x * BM;

    for (int idx = tid; idx < BM * CIN; idx += 256) {
        int r = idx / CIN;
        int k = idx - r * CIN;
        int gr = row0 + r;
        As[r * CINP + k] = (gr < NN) ? A[(size_t)gr * lda + k] : 0.0f;
    }
    __syncthreads();

    const int cg = tid % CG, rg = tid / CG;
    const int c0 = cg * 4, r0 = rg * 4;
    float acc[4][4];
#pragma unroll
    for (int i = 0; i < 4; i++)
#pragma unroll
        for (int j = 0; j < 4; j++) acc[i][j] = 0.0f;

#pragma unroll 4
    for (int k = 0; k < CIN; k++) {
        const float4 wv = *reinterpret_cast<const float4*>(&W[k * NOUT + c0]);
#pragma unroll
        for (int i = 0; i < 4; i++) {
            const float a = As[(r0 + i) * CINP + k];
            acc[i][0] = fmaf(a, wv.x, acc[i][0]);
            acc[i][1] = fmaf(a, wv.y, acc[i][1]);
            acc[i][2] = fmaf(a, wv.z, acc[i][2]);
            acc[i][3] = fmaf(a, wv.w, acc[i][3]);
        }
    }

#pragma unroll
    for (int i = 0; i < 4; i++) {
        int r = row0 + r0 + i;
        if (r < NN) {
            float4 v;
            if (BR) {
                v.x = fmaxf(acc[i][0] + bias[c0 + 0], 0.0f);
                v.y = fmaxf(acc[i][1] + bias[c0 + 1], 0.0f);
                v.z = fmaxf(acc[i][2] + bias[c0 + 2], 0.0f);
                v.w = fmaxf(acc[i][3] + bias[c0 + 3], 0.0f);
            } else {
                v.x = acc[i][0]; v.y = acc[i][1]; v.z = acc[i][2]; v.w = acc[i][3];
            }
            *reinterpret_cast<float4*>(&C[(size_t)r * ldc + c0]) = v;
        }
    }
}

// ---------------- fused gather + self-loop + bias + BN + ReLU + concat-write ----------------

template<bool DUP>
__global__ __launch_bounds__(256) void gather_bn_relu(
        const float* __restrict__ hw,
        const int* __restrict__ rowptr,
        const int* __restrict__ esrc,
        const float* __restrict__ ecoef,
        const float* __restrict__ dinv,
        const float* __restrict__ b, const float* __restrict__ g,
        const float* __restrict__ beta, const float* __restrict__ rm,
        const float* __restrict__ rv,
        float* __restrict__ Hs) {
    const int wid = (blockIdx.x * 256 + threadIdx.x) >> 6;  // node id
    const int ch = threadIdx.x & 63;
    if (wid >= NN) return;
    const int beg = rowptr[wid], end = rowptr[wid + 1];
    const float di = dinv[wid];
    float acc = hw[wid * 64 + ch] * di * di;  // self-loop
    int e = beg;
    for (; e + 1 < end; e += 2) {
        int s0 = esrc[e], s1 = esrc[e + 1];
        float c0 = ecoef[e], c1 = ecoef[e + 1];
        acc = fmaf(hw[s0 * 64 + ch], c0, acc);
        acc = fmaf(hw[s1 * 64 + ch], c1, acc);
    }
    if (e < end) {
        acc = fmaf(hw[esrc[e] * 64 + ch], ecoef[e], acc);
    }
    float sc = g[ch] * rsqrtf(rv[ch] + BN_EPS);
    float v = (acc + b[ch] - rm[ch]) * sc + beta[ch];
    v = fmaxf(v, 0.0f);
    Hs[wid * 256 + ch] = v;
    if (DUP) Hs[wid * 256 + 64 + ch] = v;
}

// ---------------- per-graph mean pooling (512 blocks, LDS reduce, 8-way partials) ----------------

__global__ __launch_bounds__(256) void pool_kernel(
        const float* __restrict__ e, const int* __restrict__ batch,
        float* __restrict__ gfeat_part, float* __restrict__ counts_part) {
    __shared__ float sh[4][NG][64];
    __shared__ float shc[4][NG];
    const int tid = threadIdx.x;
    const int ch = tid & 63;
    const int rg = tid >> 6;  // 0..3
    float acc[NG];
    float cnt[NG];
#pragma unroll
    for (int g = 0; g < NG; g++) { acc[g] = 0.0f; cnt[g] = 0.0f; }
    for (int i = blockIdx.x * 4 + rg; i < NN; i += POOL_BLOCKS * 4) {
        int b = batch[i];
        float v = e[i * 64 + ch];
#pragma unroll
        for (int g = 0; g < NG; g++) {
            acc[g] += (b == g) ? v : 0.0f;
            cnt[g] += (b == g) ? 1.0f : 0.0f;
        }
    }
#pragma unroll
    for (int g = 0; g < NG; g++) sh[rg][g][ch] = acc[g];
    if (ch == 0) {
#pragma unroll
        for (int g = 0; g < NG; g++) shc[rg][g] = cnt[g];
    }
    __syncthreads();
    const int p = blockIdx.x & (NPART - 1);
    if (rg == 0) {
#pragma unroll
        for (int g = 0; g < NG; g++) {
            float s = sh[0][g][ch] + sh[1][g][ch] + sh[2][g][ch] + sh[3][g][ch];
            atomicAdd(&gfeat_part[(p * NG + g) * 64 + ch], s);
        }
    }
    if (tid < NG) {
        float s = shc[0][tid] + shc[1][tid] + shc[2][tid] + shc[3][tid];
        atomicAdd(&counts_part[p * NG + tid], s);
    }
}

// ---------------- decoder (sums the 8 partials first) ----------------

__global__ __launch_bounds__(256) void dec_kernel(
        const float* __restrict__ gfeat_part, const float* __restrict__ counts_part,
        const float* __restrict__ w0, const float* __restrict__ b0,
        const float* __restrict__ w1, const float* __restrict__ b1,
        float* __restrict__ out) {
    __shared__ float mg[NG][64];
    __shared__ float mc[NG];
    __shared__ float t1[NG][32];
    const int tid = threadIdx.x;
    for (int idx = tid; idx < NG * 64; idx += 256) {
        float s = 0.0f;
#pragma unroll
        for (int p = 0; p < NPART; p++) s += gfeat_part[p * NG * 64 + idx];
        mg[idx >> 6][idx & 63] = s;
    }
    if (tid < NG) {
        float s = 0.0f;
#pragma unroll
        for (int p = 0; p < NPART; p++) s += counts_part[p * NG + tid];
        mc[tid] = s;
    }
    __syncthreads();
    const int g = tid >> 5, c = tid & 31;
    float inv = 1.0f / fmaxf(mc[g], 1.0f);
    float acc = b0[c];
    for (int k = 0; k < 64; k++)
        acc = fmaf(mg[g][k] * inv, w0[k * 32 + c], acc);
    t1[g][c] = fmaxf(acc, 0.0f);
    __syncthreads();
    if (tid < NG) {
        float o = b1[0];
        for (int c2 = 0; c2 < 32; c2++) o = fmaf(t1[tid][c2], w1[c2], o);
        out[tid] = o;
    }
}

// ---------------- launch ----------------

extern "C" void kernel_launch(void* const* d_in, const int* in_sizes, int n_in,
                              void* d_out, int out_size, void* d_ws, size_t ws_size,
                              hipStream_t stream) {
    const float* x      = (const float*)d_in[0];
    const int*   ei     = (const int*)d_in[1];
    const int*   batch  = (const int*)d_in[2];
    const float* W0     = (const float*)d_in[3];
    const float* b0     = (const float*)d_in[4];
    const float* g0     = (const float*)d_in[5];
    const float* beta0  = (const float*)d_in[6];
    const float* rm0    = (const float*)d_in[7];
    const float* rv0    = (const float*)d_in[8];
    const float* W1     = (const float*)d_in[9];
    const float* b1     = (const float*)d_in[10];
    const float* g1     = (const float*)d_in[11];
    const float* beta1  = (const float*)d_in[12];
    const float* rm1    = (const float*)d_in[13];
    const float* rv1    = (const float*)d_in[14];
    const float* W2     = (const float*)d_in[15];
    const float* b2     = (const float*)d_in[16];
    const float* g2     = (const float*)d_in[17];
    const float* beta2  = (const float*)d_in[18];
    const float* rm2    = (const float*)d_in[19];
    const float* rv2    = (const float*)d_in[20];
    const float* enc_w0 = (const float*)d_in[21];
    const float* enc_b0 = (const float*)d_in[22];
    const float* enc_w1 = (const float*)d_in[23];
    const float* enc_b1 = (const float*)d_in[24];
    const float* dec_w0 = (const float*)d_in[25];
    const float* dec_b0 = (const float*)d_in[26];
    const float* dec_w1 = (const float*)d_in[27];
    const float* dec_b1 = (const float*)d_in[28];

    const int* esrc = ei;
    const int* edst = ei + NE;

    // workspace layout (floats); U region aliased: CSR lives there until the
    // last gather, then enc-hidden T reuses it.
    float* ws = (float*)d_ws;
    float* H      = ws;                            // [NN,256] = [c0|c0|c1|c2]
    float* U      = H + (size_t)NN * 256;          // union region
    float* T      = U;                             // [NN,128] enc hidden
    int*   degi   = (int*)U;                       // [NN]
    int*   rowptr = degi + NN;                     // [NN+1]
    int*   cursor = rowptr + NN + 1;               // [NN]
    int*   esrc_s = cursor + NN;                   // [NE]
    float* ecoef_s= (float*)(esrc_s + NE);         // [NE]
    float* hw     = U + (size_t)NN * 128;          // [NN,64]
    float* dinv   = hw + (size_t)NN * 64;          // [NN]
    float* gfeat_part  = dinv + NN;                // [8][NG][64]
    float* counts_part = gfeat_part + NPART * NG * 64;  // [8][NG]
    int*   bsum   = (int*)(counts_part + NPART * NG);   // [NBLK]

    hipMemsetAsync(gfeat_part, 0, (NPART * NG * 64 + NPART * NG) * sizeof(float), stream);
    hipMemsetAsync(degi, 0, NN * sizeof(int), stream);

    // CSR build
    count_deg<<<(NE + 255) / 256, 256, 0, stream>>>(edst, degi);
    compute_dinv<<<NBLK, 256, 0, stream>>>(degi, dinv);
    scan_partial<<<NBLK, 256, 0, stream>>>(degi, rowptr, bsum);
    scan_bsums<<<1, 256, 0, stream>>>(bsum);
    scan_finalize<<<NBLK, 256, 0, stream>>>(bsum, rowptr, cursor);
    fill_csr<<<(NE + 255) / 256, 256, 0, stream>>>(esrc, edst, dinv, cursor, esrc_s, ecoef_s);

    const int GRID_MM64  = (NN + 63) / 64;
    const int GRID_MM128 = (NN + 31) / 32;
    const int GRID_GATH  = (NN * 64 + 255) / 256;

    // ---- layer 0: x[N,3] -> c0 (cols 0-63, dup 64-127) ----
    matmul_kernel<3, 64, false><<<GRID_MM64, 256, 0, stream>>>(x, 3, W0, nullptr, hw, 64);
    gather_bn_relu<true><<<GRID_GATH, 256, 0, stream>>>(hw, rowptr, esrc_s, ecoef_s, dinv,
                                                        b0, g0, beta0, rm0, rv0, H + 0);

    // ---- layer 1: h0 (H+0, 64) -> c1 (cols 128-191) ----
    matmul_kernel<64, 64, false><<<GRID_MM64, 256, 0, stream>>>(H, 256, W1, nullptr, hw, 64);
    gather_bn_relu<false><<<GRID_GATH, 256, 0, stream>>>(hw, rowptr, esrc_s, ecoef_s, dinv,
                                                         b1, g1, beta1, rm1, rv1, H + 128);

    // ---- layer 2: h1cat (H+64, 128) -> c2 (cols 192-255) ----
    matmul_kernel<128, 64, false><<<GRID_MM64, 256, 0, stream>>>(H + 64, 256, W2, nullptr, hw, 64);
    gather_bn_relu<false><<<GRID_GATH, 256, 0, stream>>>(hw, rowptr, esrc_s, ecoef_s, dinv,
                                                         b2, g2, beta2, rm2, rv2, H + 192);

    // ---- encoder (T overwrites CSR region; CSR dead from here) ----
    matmul_kernel<256, 128, true><<<GRID_MM128, 256, 0, stream>>>(H, 256, enc_w0, enc_b0, T, 128);
    matmul_kernel<128, 64, true><<<GRID_MM64, 256, 0, stream>>>(T, 128, enc_w1, enc_b1, hw, 64);

    // ---- pool + decode ----
    pool_kernel<<<POOL_BLOCKS, 256, 0, stream>>>(hw, batch, gfeat_part, counts_part);
    dec_kernel<<<1, 256, 0, stream>>>(gfeat_part, counts_part, dec_w0, dec_b0, dec_w1, dec_b1, (float*)d_out);
}

// Round 5
// 352.197 us; speedup vs baseline: 2.4913x; 1.2303x over previous
//
#include <hip/hip_runtime.h>

#define NN 50000
#define NE 800000
#define NG 8
#define BN_EPS 1e-5f
#define NBLK ((NN + 255) / 256)
#define POOL_BLOCKS 512
#define NPART 8

typedef __attribute__((ext_vector_type(8))) short bf16x8;
typedef __attribute__((ext_vector_type(4))) float f32x4;

static __device__ __forceinline__ unsigned short f2bf(float f) {
    unsigned int u = __float_as_uint(f);
    unsigned int r = (u + 0x7FFFu + ((u >> 16) & 1u)) >> 16;   // RNE
    return (unsigned short)r;
}
static __device__ __forceinline__ float bf2f(unsigned short h) {
    return __uint_as_float((unsigned int)h << 16);
}

// ---------------- CSR build ----------------

__global__ __launch_bounds__(256) void count_deg(const int* __restrict__ dst,
                                                 int* __restrict__ degi) {
    int e = blockIdx.x * 256 + threadIdx.x;
    if (e < NE) atomicAdd(&degi[dst[e]], 1);
}

__global__ __launch_bounds__(256) void compute_dinv(const int* __restrict__ degi,
                                                    float* __restrict__ dinv) {
    int i = blockIdx.x * 256 + threadIdx.x;
    if (i < NN) dinv[i] = rsqrtf((float)(degi[i] + 1));
}

__global__ __launch_bounds__(256) void scan_partial(const int* __restrict__ degi,
                                                    int* __restrict__ rowptr,
                                                    int* __restrict__ bsum) {
    __shared__ int sh[256];
    const int tid = threadIdx.x;
    const int i = blockIdx.x * 256 + tid;
    int v = (i < NN) ? degi[i] : 0;
    sh[tid] = v;
    __syncthreads();
#pragma unroll
    for (int off = 1; off < 256; off <<= 1) {
        int t = (tid >= off) ? sh[tid - off] : 0;
        __syncthreads();
        sh[tid] += t;
        __syncthreads();
    }
    if (i < NN) rowptr[i] = sh[tid] - v;
    if (tid == 255) bsum[blockIdx.x] = sh[255];
}

__global__ __launch_bounds__(256) void scan_bsums(int* __restrict__ bsum) {
    __shared__ int sh[256];
    const int tid = threadIdx.x;
    int v = (tid < NBLK) ? bsum[tid] : 0;
    sh[tid] = v;
    __syncthreads();
#pragma unroll
    for (int off = 1; off < 256; off <<= 1) {
        int t = (tid >= off) ? sh[tid - off] : 0;
        __syncthreads();
        sh[tid] += t;
        __syncthreads();
    }
    if (tid < NBLK) bsum[tid] = sh[tid] - v;
}

__global__ __launch_bounds__(256) void scan_finalize(const int* __restrict__ bsum,
                                                     int* __restrict__ rowptr,
                                                     int* __restrict__ cursor) {
    const int i = blockIdx.x * 256 + threadIdx.x;
    if (i < NN) {
        int r = rowptr[i] + bsum[blockIdx.x];
        rowptr[i] = r;
        cursor[i] = r;
    }
    if (i == 0) rowptr[NN] = NE;
}

__global__ __launch_bounds__(256) void fill_csr(const int* __restrict__ src,
                                                const int* __restrict__ dst,
                                                const float* __restrict__ dinv,
                                                int* __restrict__ cursor,
                                                int* __restrict__ esrc_s,
                                                float* __restrict__ ecoef_s) {
    int e = blockIdx.x * 256 + threadIdx.x;
    if (e < NE) {
        int s = src[e], d = dst[e];
        int p = atomicAdd(&cursor[d], 1);
        esrc_s[p] = s;
        ecoef_s[p] = dinv[s] * dinv[d];
    }
}

// ---------------- W pack: fp32 [K,NOUT] -> hi/lo bf16 in B-fragment order ----------------
// packed idx = ((ks*NF + f)*64 + lane)*8 + j ; k = ks*32+(lane>>4)*8+j ; col = f*16+(lane&15)

__global__ __launch_bounds__(256) void pack_w(const float* __restrict__ W, int K, int NOUT,
                                              unsigned short* __restrict__ ph,
                                              unsigned short* __restrict__ pl) {
    int idx = blockIdx.x * 256 + threadIdx.x;
    if (idx >= K * NOUT) return;
    int j = idx & 7;
    int lane = (idx >> 3) & 63;
    int rest = idx >> 9;             // ks*NF + f
    int NF = NOUT >> 4;
    int f = rest % NF, ks = rest / NF;
    int k = ks * 32 + (lane >> 4) * 8 + j;
    int col = f * 16 + (lane & 15);
    float v = W[k * NOUT + col];
    unsigned short hi = f2bf(v);
    ph[idx] = hi;
    pl[idx] = f2bf(v - bf2f(hi));
}

// ---------------- split-bf16 MFMA GEMM ----------------
// out[N, NF*16] = A[N, K] @ W[K, NF*16]; A given as hi/lo bf16 (row stride lda).
// MODE 0: write fp32, no bias. MODE 1: bias+relu, write hi/lo bf16. MODE 2: bias+relu, fp32.

template<int K, int NF, int MODE>
__global__ __launch_bounds__(256) void mfma_gemm(
        const unsigned short* __restrict__ Ahi,
        const unsigned short* __restrict__ Alo, int lda,
        const unsigned short* __restrict__ Bph,
        const unsigned short* __restrict__ Bpl,
        const float* __restrict__ bias,
        float* __restrict__ outF,
        unsigned short* __restrict__ outHi,
        unsigned short* __restrict__ outLo, int ldo) {
    const int wave = threadIdx.x >> 6;
    const int lane = threadIdx.x & 63;
    const int rbase = blockIdx.x * 64 + wave * 16;
    int arow = rbase + (lane & 15);
    if (arow >= NN) arow = NN - 1;               // clamp; masked on store
    const int kbase = (lane >> 4) * 8;

    f32x4 acc[NF];
#pragma unroll
    for (int f = 0; f < NF; f++) acc[f] = (f32x4){0.f, 0.f, 0.f, 0.f};

    const unsigned short* pa_hi = Ahi + (size_t)arow * lda + kbase;
    const unsigned short* pa_lo = Alo + (size_t)arow * lda + kbase;
    const unsigned short* pb_hi = Bph + lane * 8;
    const unsigned short* pb_lo = Bpl + lane * 8;

#pragma unroll
    for (int ks = 0; ks < K / 32; ks++) {
        bf16x8 ah = *reinterpret_cast<const bf16x8*>(pa_hi + ks * 32);
        bf16x8 al = *reinterpret_cast<const bf16x8*>(pa_lo + ks * 32);
#pragma unroll
        for (int f = 0; f < NF; f++) {
            bf16x8 bh = *reinterpret_cast<const bf16x8*>(pb_hi + (size_t)((ks * NF + f) * 64) * 8);
            bf16x8 bl = *reinterpret_cast<const bf16x8*>(pb_lo + (size_t)((ks * NF + f) * 64) * 8);
            acc[f] = __builtin_amdgcn_mfma_f32_16x16x32_bf16(ah, bh, acc[f], 0, 0, 0);
            acc[f] = __builtin_amdgcn_mfma_f32_16x16x32_bf16(ah, bl, acc[f], 0, 0, 0);
            acc[f] = __builtin_amdgcn_mfma_f32_16x16x32_bf16(al, bh, acc[f], 0, 0, 0);
        }
    }

    const int drow0 = rbase + (lane >> 4) * 4;
    const int dcol = lane & 15;
#pragma unroll
    for (int f = 0; f < NF; f++) {
#pragma unroll
        for (int r = 0; r < 4; r++) {
            int row = drow0 + r;
            if (row < NN) {
                int col = f * 16 + dcol;
                float v = acc[f][r];
                if (MODE >= 1) v = fmaxf(v + bias[col], 0.0f);
                if (MODE == 1) {
                    unsigned short hi = f2bf(v);
                    outHi[(size_t)row * ldo + col] = hi;
                    outLo[(size_t)row * ldo + col] = f2bf(v - bf2f(hi));
                } else {
                    outF[(size_t)row * ldo + col] = v;
                }
            }
        }
    }
}

// ---------------- SIMT matmul for layer 0 (CIN=3, tiny) ----------------

__global__ __launch_bounds__(256) void matmul3(const float* __restrict__ A,
                                               const float* __restrict__ W,
                                               float* __restrict__ C) {
    // thread = (node pair, 32 col-group? ) simple: 4 rows x 1 col per thread
    const int tid = blockIdx.x * 256 + threadIdx.x;
    const int row = tid >> 6;
    const int col = tid & 63;
    if (row >= NN) return;
    float a0 = A[row * 3 + 0], a1 = A[row * 3 + 1], a2 = A[row * 3 + 2];
    float v = a0 * W[0 * 64 + col] + a1 * W[1 * 64 + col] + a2 * W[2 * 64 + col];
    C[row * 64 + col] = v;
}

// ---------------- fused gather + self-loop + bias + BN + ReLU -> bf16 hi/lo concat ----------------

template<bool DUP>
__global__ __launch_bounds__(256) void gather_bn_relu(
        const float* __restrict__ hw,
        const int* __restrict__ rowptr,
        const int* __restrict__ esrc,
        const float* __restrict__ ecoef,
        const float* __restrict__ dinv,
        const float* __restrict__ b, const float* __restrict__ g,
        const float* __restrict__ beta, const float* __restrict__ rm,
        const float* __restrict__ rv,
        unsigned short* __restrict__ Hhi, unsigned short* __restrict__ Hlo) {
    const int wid = (blockIdx.x * 256 + threadIdx.x) >> 6;
    const int ch = threadIdx.x & 63;
    if (wid >= NN) return;
    const int beg = rowptr[wid], end = rowptr[wid + 1];
    const float di = dinv[wid];
    float acc = hw[wid * 64 + ch] * di * di;
    int e = beg;
    for (; e + 1 < end; e += 2) {
        int s0 = esrc[e], s1 = esrc[e + 1];
        float c0 = ecoef[e], c1 = ecoef[e + 1];
        acc = fmaf(hw[s0 * 64 + ch], c0, acc);
        acc = fmaf(hw[s1 * 64 + ch], c1, acc);
    }
    if (e < end) acc = fmaf(hw[esrc[e] * 64 + ch], ecoef[e], acc);
    float sc = g[ch] * rsqrtf(rv[ch] + BN_EPS);
    float v = (acc + b[ch] - rm[ch]) * sc + beta[ch];
    v = fmaxf(v, 0.0f);
    unsigned short hi = f2bf(v);
    unsigned short lo = f2bf(v - bf2f(hi));
    Hhi[wid * 256 + ch] = hi;
    Hlo[wid * 256 + ch] = lo;
    if (DUP) {
        Hhi[wid * 256 + 64 + ch] = hi;
        Hlo[wid * 256 + 64 + ch] = lo;
    }
}

// ---------------- per-graph mean pooling ----------------

__global__ __launch_bounds__(256) void pool_kernel(
        const float* __restrict__ e, const int* __restrict__ batch,
        float* __restrict__ gfeat_part, float* __restrict__ counts_part) {
    __shared__ float sh[4][NG][64];
    __shared__ float shc[4][NG];
    const int tid = threadIdx.x;
    const int ch = tid & 63;
    const int rg = tid >> 6;
    float acc[NG];
    float cnt[NG];
#pragma unroll
    for (int g = 0; g < NG; g++) { acc[g] = 0.0f; cnt[g] = 0.0f; }
    for (int i = blockIdx.x * 4 + rg; i < NN; i += POOL_BLOCKS * 4) {
        int b = batch[i];
        float v = e[i * 64 + ch];
#pragma unroll
        for (int g = 0; g < NG; g++) {
            acc[g] += (b == g) ? v : 0.0f;
            cnt[g] += (b == g) ? 1.0f : 0.0f;
        }
    }
#pragma unroll
    for (int g = 0; g < NG; g++) sh[rg][g][ch] = acc[g];
    if (ch == 0) {
#pragma unroll
        for (int g = 0; g < NG; g++) shc[rg][g] = cnt[g];
    }
    __syncthreads();
    const int p = blockIdx.x & (NPART - 1);
    if (rg == 0) {
#pragma unroll
        for (int g = 0; g < NG; g++) {
            float s = sh[0][g][ch] + sh[1][g][ch] + sh[2][g][ch] + sh[3][g][ch];
            atomicAdd(&gfeat_part[(p * NG + g) * 64 + ch], s);
        }
    }
    if (tid < NG) {
        float s = shc[0][tid] + shc[1][tid] + shc[2][tid] + shc[3][tid];
        atomicAdd(&counts_part[p * NG + tid], s);
    }
}

// ---------------- decoder ----------------

__global__ __launch_bounds__(256) void dec_kernel(
        const float* __restrict__ gfeat_part, const float* __restrict__ counts_part,
        const float* __restrict__ w0, const float* __restrict__ b0,
        const float* __restrict__ w1, const float* __restrict__ b1,
        float* __restrict__ out) {
    __shared__ float mg[NG][64];
    __shared__ float mc[NG];
    __shared__ float t1[NG][32];
    const int tid = threadIdx.x;
    for (int idx = tid; idx < NG * 64; idx += 256) {
        float s = 0.0f;
#pragma unroll
        for (int p = 0; p < NPART; p++) s += gfeat_part[p * NG * 64 + idx];
        mg[idx >> 6][idx & 63] = s;
    }
    if (tid < NG) {
        float s = 0.0f;
#pragma unroll
        for (int p = 0; p < NPART; p++) s += counts_part[p * NG + tid];
        mc[tid] = s;
    }
    __syncthreads();
    const int g = tid >> 5, c = tid & 31;
    float inv = 1.0f / fmaxf(mc[g], 1.0f);
    float acc = b0[c];
    for (int k = 0; k < 64; k++)
        acc = fmaf(mg[g][k] * inv, w0[k * 32 + c], acc);
    t1[g][c] = fmaxf(acc, 0.0f);
    __syncthreads();
    if (tid < NG) {
        float o = b1[0];
        for (int c2 = 0; c2 < 32; c2++) o = fmaf(t1[tid][c2], w1[c2], o);
        out[tid] = o;
    }
}

// ---------------- launch ----------------

extern "C" void kernel_launch(void* const* d_in, const int* in_sizes, int n_in,
                              void* d_out, int out_size, void* d_ws, size_t ws_size,
                              hipStream_t stream) {
    const float* x      = (const float*)d_in[0];
    const int*   ei     = (const int*)d_in[1];
    const int*   batch  = (const int*)d_in[2];
    const float* W0     = (const float*)d_in[3];
    const float* b0     = (const float*)d_in[4];
    const float* g0     = (const float*)d_in[5];
    const float* beta0  = (const float*)d_in[6];
    const float* rm0    = (const float*)d_in[7];
    const float* rv0    = (const float*)d_in[8];
    const float* W1     = (const float*)d_in[9];
    const float* b1     = (const float*)d_in[10];
    const float* g1     = (const float*)d_in[11];
    const float* beta1  = (const float*)d_in[12];
    const float* rm1    = (const float*)d_in[13];
    const float* rv1    = (const float*)d_in[14];
    const float* W2     = (const float*)d_in[15];
    const float* b2     = (const float*)d_in[16];
    const float* g2     = (const float*)d_in[17];
    const float* beta2  = (const float*)d_in[18];
    const float* rm2    = (const float*)d_in[19];
    const float* rv2    = (const float*)d_in[20];
    const float* enc_w0 = (const float*)d_in[21];
    const float* enc_b0 = (const float*)d_in[22];
    const float* enc_w1 = (const float*)d_in[23];
    const float* enc_b1 = (const float*)d_in[24];
    const float* dec_w0 = (const float*)d_in[25];
    const float* dec_b0 = (const float*)d_in[26];
    const float* dec_w1 = (const float*)d_in[27];
    const float* dec_b1 = (const float*)d_in[28];

    const int* esrc = ei;
    const int* edst = ei + NE;

    // ---- workspace layout ----
    // Hhi [NN*256 u16] | Hlo [NN*256 u16] | U (25.6MB: CSR then Thi/Tlo) |
    // hw [NN*64 f32] | dinv | pools | Wpacks
    char* wsb = (char*)d_ws;
    unsigned short* Hhi = (unsigned short*)wsb;                       // 25.6MB
    unsigned short* Hlo = Hhi + (size_t)NN * 256;                     // 25.6MB
    char* U = (char*)(Hlo + (size_t)NN * 256);                        // 25.6MB union
    unsigned short* Thi = (unsigned short*)U;                         // [NN*128]
    unsigned short* Tlo = Thi + (size_t)NN * 128;                     // [NN*128]
    int*   degi   = (int*)U;
    int*   rowptr = degi + NN;
    int*   cursor = rowptr + NN + 1;
    int*   esrc_s = cursor + NN;                                      // [NE]
    float* ecoef_s= (float*)(esrc_s + NE);                            // [NE]
    float* hw     = (float*)(U + (size_t)NN * 128 * 2 * sizeof(unsigned short));
    float* dinv   = hw + (size_t)NN * 64;
    float* gfeat_part  = dinv + NN;
    float* counts_part = gfeat_part + NPART * NG * 64;
    int*   bsum   = (int*)(counts_part + NPART * NG);
    unsigned short* wp = (unsigned short*)(bsum + NBLK);
    unsigned short* Wp1h = wp;              unsigned short* Wp1l = Wp1h + 64 * 64;
    unsigned short* Wp2h = Wp1l + 64 * 64;  unsigned short* Wp2l = Wp2h + 128 * 64;
    unsigned short* We0h = Wp2l + 128 * 64; unsigned short* We0l = We0h + 256 * 128;
    unsigned short* We1h = We0l + 256 * 128;unsigned short* We1l = We1h + 128 * 64;

    hipMemsetAsync(gfeat_part, 0, (NPART * NG * 64 + NPART * NG) * sizeof(float), stream);
    hipMemsetAsync(degi, 0, NN * sizeof(int), stream);

    // CSR build
    count_deg<<<(NE + 255) / 256, 256, 0, stream>>>(edst, degi);
    compute_dinv<<<NBLK, 256, 0, stream>>>(degi, dinv);
    scan_partial<<<NBLK, 256, 0, stream>>>(degi, rowptr, bsum);
    scan_bsums<<<1, 256, 0, stream>>>(bsum);
    scan_finalize<<<NBLK, 256, 0, stream>>>(bsum, rowptr, cursor);
    fill_csr<<<(NE + 255) / 256, 256, 0, stream>>>(esrc, edst, dinv, cursor, esrc_s, ecoef_s);

    // W packs (tiny)
    pack_w<<<(64 * 64 + 255) / 256, 256, 0, stream>>>(W1, 64, 64, Wp1h, Wp1l);
    pack_w<<<(128 * 64 + 255) / 256, 256, 0, stream>>>(W2, 128, 64, Wp2h, Wp2l);
    pack_w<<<(256 * 128 + 255) / 256, 256, 0, stream>>>(enc_w0, 256, 128, We0h, We0l);
    pack_w<<<(128 * 64 + 255) / 256, 256, 0, stream>>>(enc_w1, 128, 64, We1h, We1l);

    const int GRID_MFMA = (NN + 63) / 64;          // 782
    const int GRID_GATH = (NN * 64 + 255) / 256;

    // ---- layer 0: x[N,3] -> hw (SIMT, tiny K) ----
    matmul3<<<(NN * 64 + 255) / 256, 256, 0, stream>>>(x, W0, hw);
    gather_bn_relu<true><<<GRID_GATH, 256, 0, stream>>>(hw, rowptr, esrc_s, ecoef_s, dinv,
                                                        b0, g0, beta0, rm0, rv0, Hhi, Hlo);

    // ---- layer 1: H[:,0:64] @ W1 -> hw ----
    mfma_gemm<64, 4, 0><<<GRID_MFMA, 256, 0, stream>>>(Hhi, Hlo, 256, Wp1h, Wp1l,
                                                       nullptr, hw, nullptr, nullptr, 64);
    gather_bn_relu<false><<<GRID_GATH, 256, 0, stream>>>(hw, rowptr, esrc_s, ecoef_s, dinv,
                                                         b1, g1, beta1, rm1, rv1, Hhi + 128, Hlo + 128);

    // ---- layer 2: H[:,64:192] @ W2 -> hw ----
    mfma_gemm<128, 4, 0><<<GRID_MFMA, 256, 0, stream>>>(Hhi + 64, Hlo + 64, 256, Wp2h, Wp2l,
                                                        nullptr, hw, nullptr, nullptr, 64);
    gather_bn_relu<false><<<GRID_GATH, 256, 0, stream>>>(hw, rowptr, esrc_s, ecoef_s, dinv,
                                                         b2, g2, beta2, rm2, rv2, Hhi + 192, Hlo + 192);

    // ---- encoder (Thi/Tlo overwrite CSR region; CSR dead from here) ----
    mfma_gemm<256, 8, 1><<<GRID_MFMA, 256, 0, stream>>>(Hhi, Hlo, 256, We0h, We0l,
                                                        enc_b0, nullptr, Thi, Tlo, 128);
    mfma_gemm<128, 4, 2><<<GRID_MFMA, 256, 0, stream>>>(Thi, Tlo, 128, We1h, We1l,
                                                        enc_b1, hw, nullptr, nullptr, 64);

    // ---- pool + decode ----
    pool_kernel<<<POOL_BLOCKS, 256, 0, stream>>>(hw, batch, gfeat_part, counts_part);
    dec_kernel<<<1, 256, 0, stream>>>(gfeat_part, counts_part, dec_w0, dec_b0, dec_w1, dec_b1, (float*)d_out);
}

// Round 6
// 285.133 us; speedup vs baseline: 3.0773x; 1.2352x over previous
//
#include <hip/hip_runtime.h>

#define NN 50000
#define NE 800000
#define NG 8
#define BN_EPS 1e-5f
#define NBLK ((NN + 255) / 256)
#define POOL_BLOCKS 512
#define NPART 8

typedef __attribute__((ext_vector_type(8))) short bf16x8;
typedef __attribute__((ext_vector_type(4))) float f32x4;

static __device__ __forceinline__ unsigned short f2bf(float f) {
    unsigned int u = __float_as_uint(f);
    unsigned int r = (u + 0x7FFFu + ((u >> 16) & 1u)) >> 16;   // RNE
    return (unsigned short)r;
}
static __device__ __forceinline__ float bf2f(unsigned short h) {
    return __uint_as_float((unsigned int)h << 16);
}

// ---------------- CSR build ----------------

__global__ __launch_bounds__(256) void count_deg(const int* __restrict__ dst,
                                                 int* __restrict__ degi) {
    int e = blockIdx.x * 256 + threadIdx.x;
    if (e < NE) atomicAdd(&degi[dst[e]], 1);
}

__global__ __launch_bounds__(256) void compute_dinv(const int* __restrict__ degi,
                                                    float* __restrict__ dinv) {
    int i = blockIdx.x * 256 + threadIdx.x;
    if (i < NN) dinv[i] = rsqrtf((float)(degi[i] + 1));
}

__global__ __launch_bounds__(256) void scan_partial(const int* __restrict__ degi,
                                                    int* __restrict__ rowptr,
                                                    int* __restrict__ bsum) {
    __shared__ int sh[256];
    const int tid = threadIdx.x;
    const int i = blockIdx.x * 256 + tid;
    int v = (i < NN) ? degi[i] : 0;
    sh[tid] = v;
    __syncthreads();
#pragma unroll
    for (int off = 1; off < 256; off <<= 1) {
        int t = (tid >= off) ? sh[tid - off] : 0;
        __syncthreads();
        sh[tid] += t;
        __syncthreads();
    }
    if (i < NN) rowptr[i] = sh[tid] - v;
    if (tid == 255) bsum[blockIdx.x] = sh[255];
}

__global__ __launch_bounds__(256) void scan_bsums(int* __restrict__ bsum) {
    __shared__ int sh[256];
    const int tid = threadIdx.x;
    int v = (tid < NBLK) ? bsum[tid] : 0;
    sh[tid] = v;
    __syncthreads();
#pragma unroll
    for (int off = 1; off < 256; off <<= 1) {
        int t = (tid >= off) ? sh[tid - off] : 0;
        __syncthreads();
        sh[tid] += t;
        __syncthreads();
    }
    if (tid < NBLK) bsum[tid] = sh[tid] - v;
}

__global__ __launch_bounds__(256) void scan_finalize(const int* __restrict__ bsum,
                                                     int* __restrict__ rowptr,
                                                     int* __restrict__ cursor) {
    const int i = blockIdx.x * 256 + threadIdx.x;
    if (i < NN) {
        int r = rowptr[i] + bsum[blockIdx.x];
        rowptr[i] = r;
        cursor[i] = r;
    }
    if (i == 0) rowptr[NN] = NE;
}

__global__ __launch_bounds__(256) void fill_csr(const int* __restrict__ src,
                                                const int* __restrict__ dst,
                                                const float* __restrict__ dinv,
                                                int* __restrict__ cursor,
                                                int* __restrict__ esrc_s,
                                                float* __restrict__ ecoef_s) {
    int e = blockIdx.x * 256 + threadIdx.x;
    if (e < NE) {
        int s = src[e], d = dst[e];
        int p = atomicAdd(&cursor[d], 1);
        esrc_s[p] = s;
        ecoef_s[p] = dinv[s] * dinv[d];
    }
}

// ---------------- W pack: fp32 [K,NOUT] -> hi/lo bf16 in B-fragment order ----------------

__global__ __launch_bounds__(256) void pack_w(const float* __restrict__ W, int K, int NOUT,
                                              unsigned short* __restrict__ ph,
                                              unsigned short* __restrict__ pl) {
    int idx = blockIdx.x * 256 + threadIdx.x;
    if (idx >= K * NOUT) return;
    int j = idx & 7;
    int lane = (idx >> 3) & 63;
    int rest = idx >> 9;             // ks*NF + f
    int NF = NOUT >> 4;
    int f = rest % NF, ks = rest / NF;
    int k = ks * 32 + (lane >> 4) * 8 + j;
    int col = f * 16 + (lane & 15);
    float v = W[k * NOUT + col];
    unsigned short hi = f2bf(v);
    ph[idx] = hi;
    pl[idx] = f2bf(v - bf2f(hi));
}

// ---------------- split-bf16 MFMA GEMM ----------------
// MODE 0: fp32 out, no bias. MODE 1: bias+relu -> hi/lo bf16. MODE 2: bias+relu -> fp32.

template<int K, int NF, int MODE>
__global__ __launch_bounds__(256) void mfma_gemm(
        const unsigned short* __restrict__ Ahi,
        const unsigned short* __restrict__ Alo, int lda,
        const unsigned short* __restrict__ Bph,
        const unsigned short* __restrict__ Bpl,
        const float* __restrict__ bias,
        float* __restrict__ outF,
        unsigned short* __restrict__ outHi,
        unsigned short* __restrict__ outLo, int ldo) {
    const int wave = threadIdx.x >> 6;
    const int lane = threadIdx.x & 63;
    const int rbase = blockIdx.x * 64 + wave * 16;
    int arow = rbase + (lane & 15);
    if (arow >= NN) arow = NN - 1;
    const int kbase = (lane >> 4) * 8;

    f32x4 acc[NF];
#pragma unroll
    for (int f = 0; f < NF; f++) acc[f] = (f32x4){0.f, 0.f, 0.f, 0.f};

    const unsigned short* pa_hi = Ahi + (size_t)arow * lda + kbase;
    const unsigned short* pa_lo = Alo + (size_t)arow * lda + kbase;
    const unsigned short* pb_hi = Bph + lane * 8;
    const unsigned short* pb_lo = Bpl + lane * 8;

#pragma unroll
    for (int ks = 0; ks < K / 32; ks++) {
        bf16x8 ah = *reinterpret_cast<const bf16x8*>(pa_hi + ks * 32);
        bf16x8 al = *reinterpret_cast<const bf16x8*>(pa_lo + ks * 32);
#pragma unroll
        for (int f = 0; f < NF; f++) {
            bf16x8 bh = *reinterpret_cast<const bf16x8*>(pb_hi + (size_t)((ks * NF + f) * 64) * 8);
            bf16x8 bl = *reinterpret_cast<const bf16x8*>(pb_lo + (size_t)((ks * NF + f) * 64) * 8);
            acc[f] = __builtin_amdgcn_mfma_f32_16x16x32_bf16(ah, bh, acc[f], 0, 0, 0);
            acc[f] = __builtin_amdgcn_mfma_f32_16x16x32_bf16(ah, bl, acc[f], 0, 0, 0);
            acc[f] = __builtin_amdgcn_mfma_f32_16x16x32_bf16(al, bh, acc[f], 0, 0, 0);
        }
    }

    const int drow0 = rbase + (lane >> 4) * 4;
    const int dcol = lane & 15;
#pragma unroll
    for (int f = 0; f < NF; f++) {
#pragma unroll
        for (int r = 0; r < 4; r++) {
            int row = drow0 + r;
            if (row < NN) {
                int col = f * 16 + dcol;
                float v = acc[f][r];
                if (MODE >= 1) v = fmaxf(v + bias[col], 0.0f);
                if (MODE == 1) {
                    unsigned short hi = f2bf(v);
                    outHi[(size_t)row * ldo + col] = hi;
                    outLo[(size_t)row * ldo + col] = f2bf(v - bf2f(hi));
                } else {
                    outF[(size_t)row * ldo + col] = v;
                }
            }
        }
    }
}

// ---------------- layer 0: aggregate x (3-wide) per node ----------------

__global__ __launch_bounds__(256) void agg_x3(
        const float* __restrict__ x,
        const int* __restrict__ rowptr,
        const int* __restrict__ esrc,
        const float* __restrict__ ecoef,
        const float* __restrict__ dinv,
        float* __restrict__ ax) {
    const int i = blockIdx.x * 256 + threadIdx.x;
    if (i >= NN) return;
    const float di = dinv[i];
    const float c = di * di;
    float a0 = x[i * 3 + 0] * c;
    float a1 = x[i * 3 + 1] * c;
    float a2 = x[i * 3 + 2] * c;
    const int beg = rowptr[i], end = rowptr[i + 1];
    int e = beg;
    for (; e + 1 < end; e += 2) {
        int s0 = esrc[e], s1 = esrc[e + 1];
        float w0 = ecoef[e], w1 = ecoef[e + 1];
        a0 = fmaf(x[s0 * 3 + 0], w0, a0);
        a1 = fmaf(x[s0 * 3 + 1], w0, a1);
        a2 = fmaf(x[s0 * 3 + 2], w0, a2);
        a0 = fmaf(x[s1 * 3 + 0], w1, a0);
        a1 = fmaf(x[s1 * 3 + 1], w1, a1);
        a2 = fmaf(x[s1 * 3 + 2], w1, a2);
    }
    if (e < end) {
        int s = esrc[e];
        float w = ecoef[e];
        a0 = fmaf(x[s * 3 + 0], w, a0);
        a1 = fmaf(x[s * 3 + 1], w, a1);
        a2 = fmaf(x[s * 3 + 2], w, a2);
    }
    ax[i * 3 + 0] = a0;
    ax[i * 3 + 1] = a1;
    ax[i * 3 + 2] = a2;
}

// ---------------- layer 0 dense: c0 = relu(BN(ax @ W0 + b0)), hi/lo + dup ----------------

__global__ __launch_bounds__(256) void l0_bn_relu(
        const float* __restrict__ ax, const float* __restrict__ W0,
        const float* __restrict__ b, const float* __restrict__ g,
        const float* __restrict__ beta, const float* __restrict__ rm,
        const float* __restrict__ rv,
        unsigned short* __restrict__ Hhi, unsigned short* __restrict__ Hlo) {
    const int t = blockIdx.x * 256 + threadIdx.x;
    const int row = t >> 6;
    const int ch = t & 63;
    if (row >= NN) return;
    float a0 = ax[row * 3 + 0], a1 = ax[row * 3 + 1], a2 = ax[row * 3 + 2];
    float v = a0 * W0[0 * 64 + ch] + a1 * W0[1 * 64 + ch] + a2 * W0[2 * 64 + ch] + b[ch];
    float sc = g[ch] * rsqrtf(rv[ch] + BN_EPS);
    v = (v - rm[ch]) * sc + beta[ch];
    v = fmaxf(v, 0.0f);
    unsigned short hi = f2bf(v);
    unsigned short lo = f2bf(v - bf2f(hi));
    Hhi[row * 256 + ch] = hi;
    Hlo[row * 256 + ch] = lo;
    Hhi[row * 256 + 64 + ch] = hi;
    Hlo[row * 256 + 64 + ch] = lo;
}

// ---------------- fused gather + self-loop + bias + BN + ReLU -> hi/lo concat ----------------

__global__ __launch_bounds__(256) void gather_bn_relu(
        const float* __restrict__ hw,
        const int* __restrict__ rowptr,
        const int* __restrict__ esrc,
        const float* __restrict__ ecoef,
        const float* __restrict__ dinv,
        const float* __restrict__ b, const float* __restrict__ g,
        const float* __restrict__ beta, const float* __restrict__ rm,
        const float* __restrict__ rv,
        unsigned short* __restrict__ Hhi, unsigned short* __restrict__ Hlo) {
    const int wid = (blockIdx.x * 256 + threadIdx.x) >> 6;
    const int ch = threadIdx.x & 63;
    if (wid >= NN) return;
    const int beg = rowptr[wid], end = rowptr[wid + 1];
    const float di = dinv[wid];
    float acc = hw[wid * 64 + ch] * di * di;
    int e = beg;
    for (; e + 3 < end; e += 4) {
        int s0 = esrc[e], s1 = esrc[e + 1], s2 = esrc[e + 2], s3 = esrc[e + 3];
        float c0 = ecoef[e], c1 = ecoef[e + 1], c2 = ecoef[e + 2], c3 = ecoef[e + 3];
        float v0 = hw[s0 * 64 + ch], v1 = hw[s1 * 64 + ch];
        float v2 = hw[s2 * 64 + ch], v3 = hw[s3 * 64 + ch];
        acc = fmaf(v0, c0, acc);
        acc = fmaf(v1, c1, acc);
        acc = fmaf(v2, c2, acc);
        acc = fmaf(v3, c3, acc);
    }
    for (; e < end; e++) acc = fmaf(hw[esrc[e] * 64 + ch], ecoef[e], acc);
    float sc = g[ch] * rsqrtf(rv[ch] + BN_EPS);
    float v = (acc + b[ch] - rm[ch]) * sc + beta[ch];
    v = fmaxf(v, 0.0f);
    unsigned short hi = f2bf(v);
    unsigned short lo = f2bf(v - bf2f(hi));
    Hhi[wid * 256 + ch] = hi;
    Hlo[wid * 256 + ch] = lo;
}

// ---------------- per-graph mean pooling ----------------

__global__ __launch_bounds__(256) void pool_kernel(
        const float* __restrict__ e, const int* __restrict__ batch,
        float* __restrict__ gfeat_part, float* __restrict__ counts_part) {
    __shared__ float sh[4][NG][64];
    __shared__ float shc[4][NG];
    const int tid = threadIdx.x;
    const int ch = tid & 63;
    const int rg = tid >> 6;
    float acc[NG];
    float cnt[NG];
#pragma unroll
    for (int g = 0; g < NG; g++) { acc[g] = 0.0f; cnt[g] = 0.0f; }
    for (int i = blockIdx.x * 4 + rg; i < NN; i += POOL_BLOCKS * 4) {
        int b = batch[i];
        float v = e[i * 64 + ch];
#pragma unroll
        for (int g = 0; g < NG; g++) {
            acc[g] += (b == g) ? v : 0.0f;
            cnt[g] += (b == g) ? 1.0f : 0.0f;
        }
    }
#pragma unroll
    for (int g = 0; g < NG; g++) sh[rg][g][ch] = acc[g];
    if (ch == 0) {
#pragma unroll
        for (int g = 0; g < NG; g++) shc[rg][g] = cnt[g];
    }
    __syncthreads();
    const int p = blockIdx.x & (NPART - 1);
    if (rg == 0) {
#pragma unroll
        for (int g = 0; g < NG; g++) {
            float s = sh[0][g][ch] + sh[1][g][ch] + sh[2][g][ch] + sh[3][g][ch];
            atomicAdd(&gfeat_part[(p * NG + g) * 64 + ch], s);
        }
    }
    if (tid < NG) {
        float s = shc[0][tid] + shc[1][tid] + shc[2][tid] + shc[3][tid];
        atomicAdd(&counts_part[p * NG + tid], s);
    }
}

// ---------------- decoder ----------------

__global__ __launch_bounds__(256) void dec_kernel(
        const float* __restrict__ gfeat_part, const float* __restrict__ counts_part,
        const float* __restrict__ w0, const float* __restrict__ b0,
        const float* __restrict__ w1, const float* __restrict__ b1,
        float* __restrict__ out) {
    __shared__ float mg[NG][64];
    __shared__ float mc[NG];
    __shared__ float t1[NG][32];
    const int tid = threadIdx.x;
    for (int idx = tid; idx < NG * 64; idx += 256) {
        float s = 0.0f;
#pragma unroll
        for (int p = 0; p < NPART; p++) s += gfeat_part[p * NG * 64 + idx];
        mg[idx >> 6][idx & 63] = s;
    }
    if (tid < NG) {
        float s = 0.0f;
#pragma unroll
        for (int p = 0; p < NPART; p++) s += counts_part[p * NG + tid];
        mc[tid] = s;
    }
    __syncthreads();
    const int g = tid >> 5, c = tid & 31;
    float inv = 1.0f / fmaxf(mc[g], 1.0f);
    float acc = b0[c];
    for (int k = 0; k < 64; k++)
        acc = fmaf(mg[g][k] * inv, w0[k * 32 + c], acc);
    t1[g][c] = fmaxf(acc, 0.0f);
    __syncthreads();
    if (tid < NG) {
        float o = b1[0];
        for (int c2 = 0; c2 < 32; c2++) o = fmaf(t1[tid][c2], w1[c2], o);
        out[tid] = o;
    }
}

// ---------------- launch ----------------

extern "C" void kernel_launch(void* const* d_in, const int* in_sizes, int n_in,
                              void* d_out, int out_size, void* d_ws, size_t ws_size,
                              hipStream_t stream) {
    const float* x      = (const float*)d_in[0];
    const int*   ei     = (const int*)d_in[1];
    const int*   batch  = (const int*)d_in[2];
    const float* W0     = (const float*)d_in[3];
    const float* b0     = (const float*)d_in[4];
    const float* g0     = (const float*)d_in[5];
    const float* beta0  = (const float*)d_in[6];
    const float* rm0    = (const float*)d_in[7];
    const float* rv0    = (const float*)d_in[8];
    const float* W1     = (const float*)d_in[9];
    const float* b1     = (const float*)d_in[10];
    const float* g1     = (const float*)d_in[11];
    const float* beta1  = (const float*)d_in[12];
    const float* rm1    = (const float*)d_in[13];
    const float* rv1    = (const float*)d_in[14];
    const float* W2     = (const float*)d_in[15];
    const float* b2     = (const float*)d_in[16];
    const float* g2     = (const float*)d_in[17];
    const float* beta2  = (const float*)d_in[18];
    const float* rm2    = (const float*)d_in[19];
    const float* rv2    = (const float*)d_in[20];
    const float* enc_w0 = (const float*)d_in[21];
    const float* enc_b0 = (const float*)d_in[22];
    const float* enc_w1 = (const float*)d_in[23];
    const float* enc_b1 = (const float*)d_in[24];
    const float* dec_w0 = (const float*)d_in[25];
    const float* dec_b0 = (const float*)d_in[26];
    const float* dec_w1 = (const float*)d_in[27];
    const float* dec_b1 = (const float*)d_in[28];

    const int* esrc = ei;
    const int* edst = ei + NE;

    char* wsb = (char*)d_ws;
    unsigned short* Hhi = (unsigned short*)wsb;                       // [NN*256]
    unsigned short* Hlo = Hhi + (size_t)NN * 256;                     // [NN*256]
    char* U = (char*)(Hlo + (size_t)NN * 256);                        // union
    unsigned short* Thi = (unsigned short*)U;                         // [NN*128]
    unsigned short* Tlo = Thi + (size_t)NN * 128;                     // [NN*128]
    int*   degi   = (int*)U;
    int*   rowptr = degi + NN;
    int*   cursor = rowptr + NN + 1;
    int*   esrc_s = cursor + NN;                                      // [NE]
    float* ecoef_s= (float*)(esrc_s + NE);                            // [NE]
    float* hw     = (float*)(U + (size_t)NN * 128 * 2 * sizeof(unsigned short));
    float* dinv   = hw + (size_t)NN * 64;
    float* gfeat_part  = dinv + NN;
    float* counts_part = gfeat_part + NPART * NG * 64;
    int*   bsum   = (int*)(counts_part + NPART * NG);
    float* ax     = (float*)(bsum + NBLK);                            // [NN*3]
    unsigned short* wp = (unsigned short*)(ax + (size_t)NN * 3);
    unsigned short* Wp1h = wp;              unsigned short* Wp1l = Wp1h + 64 * 64;
    unsigned short* Wp2h = Wp1l + 64 * 64;  unsigned short* Wp2l = Wp2h + 128 * 64;
    unsigned short* We0h = Wp2l + 128 * 64; unsigned short* We0l = We0h + 256 * 128;
    unsigned short* We1h = We0l + 256 * 128;unsigned short* We1l = We1h + 128 * 64;

    hipMemsetAsync(gfeat_part, 0, (NPART * NG * 64 + NPART * NG) * sizeof(float), stream);
    hipMemsetAsync(degi, 0, NN * sizeof(int), stream);

    // CSR build
    count_deg<<<(NE + 255) / 256, 256, 0, stream>>>(edst, degi);
    compute_dinv<<<NBLK, 256, 0, stream>>>(degi, dinv);
    scan_partial<<<NBLK, 256, 0, stream>>>(degi, rowptr, bsum);
    scan_bsums<<<1, 256, 0, stream>>>(bsum);
    scan_finalize<<<NBLK, 256, 0, stream>>>(bsum, rowptr, cursor);
    fill_csr<<<(NE + 255) / 256, 256, 0, stream>>>(esrc, edst, dinv, cursor, esrc_s, ecoef_s);

    // W packs
    pack_w<<<(64 * 64 + 255) / 256, 256, 0, stream>>>(W1, 64, 64, Wp1h, Wp1l);
    pack_w<<<(128 * 64 + 255) / 256, 256, 0, stream>>>(W2, 128, 64, Wp2h, Wp2l);
    pack_w<<<(256 * 128 + 255) / 256, 256, 0, stream>>>(enc_w0, 256, 128, We0h, We0l);
    pack_w<<<(128 * 64 + 255) / 256, 256, 0, stream>>>(enc_w1, 128, 64, We1h, We1l);

    const int GRID_MFMA = (NN + 63) / 64;
    const int GRID_GATH = (NN * 64 + 255) / 256;

    // ---- layer 0: aggregate x (3-wide) then fused dense+BN+relu (dup write) ----
    agg_x3<<<NBLK, 256, 0, stream>>>(x, rowptr, esrc_s, ecoef_s, dinv, ax);
    l0_bn_relu<<<GRID_GATH, 256, 0, stream>>>(ax, W0, b0, g0, beta0, rm0, rv0, Hhi, Hlo);

    // ---- layer 1: H[:,0:64] @ W1 -> hw ; gather -> cols 128-191 ----
    mfma_gemm<64, 4, 0><<<GRID_MFMA, 256, 0, stream>>>(Hhi, Hlo, 256, Wp1h, Wp1l,
                                                       nullptr, hw, nullptr, nullptr, 64);
    gather_bn_relu<<<GRID_GATH, 256, 0, stream>>>(hw, rowptr, esrc_s, ecoef_s, dinv,
                                                  b1, g1, beta1, rm1, rv1, Hhi + 128, Hlo + 128);

    // ---- layer 2: H[:,64:192] @ W2 -> hw ; gather -> cols 192-255 ----
    mfma_gemm<128, 4, 0><<<GRID_MFMA, 256, 0, stream>>>(Hhi + 64, Hlo + 64, 256, Wp2h, Wp2l,
                                                        nullptr, hw, nullptr, nullptr, 64);
    gather_bn_relu<<<GRID_GATH, 256, 0, stream>>>(hw, rowptr, esrc_s, ecoef_s, dinv,
                                                  b2, g2, beta2, rm2, rv2, Hhi + 192, Hlo + 192);

    // ---- encoder (Thi/Tlo overwrite CSR region; CSR dead from here) ----
    mfma_gemm<256, 8, 1><<<GRID_MFMA, 256, 0, stream>>>(Hhi, Hlo, 256, We0h, We0l,
                                                        enc_b0, nullptr, Thi, Tlo, 128);
    mfma_gemm<128, 4, 2><<<GRID_MFMA, 256, 0, stream>>>(Thi, Tlo, 128, We1h, We1l,
                                                        enc_b1, hw, nullptr, nullptr, 64);

    // ---- pool + decode ----
    pool_kernel<<<POOL_BLOCKS, 256, 0, stream>>>(hw, batch, gfeat_part, counts_part);
    dec_kernel<<<1, 256, 0, stream>>>(gfeat_part, counts_part, dec_w0, dec_b0, dec_w1, dec_b1, (float*)d_out);
}

// Round 7
// 279.769 us; speedup vs baseline: 3.1363x; 1.0192x over previous
//
#include <hip/hip_runtime.h>

#define NN 50000
#define NE 800000
#define NG 8
#define BN_EPS 1e-5f
#define NBLK ((NN + 255) / 256)
#define POOL_BLOCKS 512
#define NPART 8

typedef __attribute__((ext_vector_type(8))) short bf16x8;
typedef __attribute__((ext_vector_type(4))) float f32x4;

static __device__ __forceinline__ unsigned short f2bf(float f) {
    unsigned int u = __float_as_uint(f);
    unsigned int r = (u + 0x7FFFu + ((u >> 16) & 1u)) >> 16;   // RNE
    return (unsigned short)r;
}
static __device__ __forceinline__ float bf2f(unsigned short h) {
    return __uint_as_float((unsigned int)h << 16);
}

// ---------------- CSR build ----------------

__global__ __launch_bounds__(256) void count_deg(const int* __restrict__ dst,
                                                 int* __restrict__ degi) {
    int e = blockIdx.x * 256 + threadIdx.x;
    if (e < NE) atomicAdd(&degi[dst[e]], 1);
}

// dinv + xs = x * dinv (layer-0 pre-scaled features)
__global__ __launch_bounds__(256) void compute_dinv_xs(const int* __restrict__ degi,
                                                       const float* __restrict__ x,
                                                       float* __restrict__ dinv,
                                                       float* __restrict__ xs) {
    int i = blockIdx.x * 256 + threadIdx.x;
    if (i < NN) {
        float di = rsqrtf((float)(degi[i] + 1));
        dinv[i] = di;
        xs[i * 3 + 0] = x[i * 3 + 0] * di;
        xs[i * 3 + 1] = x[i * 3 + 1] * di;
        xs[i * 3 + 2] = x[i * 3 + 2] * di;
    }
}

__global__ __launch_bounds__(256) void scan_partial(const int* __restrict__ degi,
                                                    int* __restrict__ rowptr,
                                                    int* __restrict__ bsum) {
    __shared__ int sh[256];
    const int tid = threadIdx.x;
    const int i = blockIdx.x * 256 + tid;
    int v = (i < NN) ? degi[i] : 0;
    sh[tid] = v;
    __syncthreads();
#pragma unroll
    for (int off = 1; off < 256; off <<= 1) {
        int t = (tid >= off) ? sh[tid - off] : 0;
        __syncthreads();
        sh[tid] += t;
        __syncthreads();
    }
    if (i < NN) rowptr[i] = sh[tid] - v;
    if (tid == 255) bsum[blockIdx.x] = sh[255];
}

__global__ __launch_bounds__(256) void scan_bsums(int* __restrict__ bsum) {
    __shared__ int sh[256];
    const int tid = threadIdx.x;
    int v = (tid < NBLK) ? bsum[tid] : 0;
    sh[tid] = v;
    __syncthreads();
#pragma unroll
    for (int off = 1; off < 256; off <<= 1) {
        int t = (tid >= off) ? sh[tid - off] : 0;
        __syncthreads();
        sh[tid] += t;
        __syncthreads();
    }
    if (tid < NBLK) bsum[tid] = sh[tid] - v;
}

__global__ __launch_bounds__(256) void scan_finalize(const int* __restrict__ bsum,
                                                     int* __restrict__ rowptr,
                                                     int* __restrict__ cursor) {
    const int i = blockIdx.x * 256 + threadIdx.x;
    if (i < NN) {
        int r = rowptr[i] + bsum[blockIdx.x];
        rowptr[i] = r;
        cursor[i] = r;
    }
    if (i == 0) rowptr[NN] = NE;
}

// scatter only a u16 src index per edge (no coefficient!)
__global__ __launch_bounds__(256) void fill_csr(const int* __restrict__ src,
                                                const int* __restrict__ dst,
                                                int* __restrict__ cursor,
                                                unsigned short* __restrict__ esrc16) {
    int e = blockIdx.x * 256 + threadIdx.x;
    if (e < NE) {
        int s = src[e], d = dst[e];
        int p = atomicAdd(&cursor[d], 1);
        esrc16[p] = (unsigned short)s;
    }
}

// ---------------- W pack: fp32 [K,NOUT] -> hi/lo bf16 in B-fragment order ----------------

__global__ __launch_bounds__(256) void pack_w(const float* __restrict__ W, int K, int NOUT,
                                              unsigned short* __restrict__ ph,
                                              unsigned short* __restrict__ pl) {
    int idx = blockIdx.x * 256 + threadIdx.x;
    if (idx >= K * NOUT) return;
    int j = idx & 7;
    int lane = (idx >> 3) & 63;
    int rest = idx >> 9;             // ks*NF + f
    int NF = NOUT >> 4;
    int f = rest % NF, ks = rest / NF;
    int k = ks * 32 + (lane >> 4) * 8 + j;
    int col = f * 16 + (lane & 15);
    float v = W[k * NOUT + col];
    unsigned short hi = f2bf(v);
    ph[idx] = hi;
    pl[idx] = f2bf(v - bf2f(hi));
}

// ---------------- split-bf16 MFMA GEMM ----------------
// MODE 0: out = (A@W) * dinv[row]  (pre-scaled aggregation input), fp32
// MODE 1: bias+relu -> hi/lo bf16. MODE 2: bias+relu -> fp32.

template<int K, int NF, int MODE>
__global__ __launch_bounds__(256) void mfma_gemm(
        const unsigned short* __restrict__ Ahi,
        const unsigned short* __restrict__ Alo, int lda,
        const unsigned short* __restrict__ Bph,
        const unsigned short* __restrict__ Bpl,
        const float* __restrict__ bias,
        const float* __restrict__ dinv,
        float* __restrict__ outF,
        unsigned short* __restrict__ outHi,
        unsigned short* __restrict__ outLo, int ldo) {
    const int wave = threadIdx.x >> 6;
    const int lane = threadIdx.x & 63;
    const int rbase = blockIdx.x * 64 + wave * 16;
    int arow = rbase + (lane & 15);
    if (arow >= NN) arow = NN - 1;
    const int kbase = (lane >> 4) * 8;

    f32x4 acc[NF];
#pragma unroll
    for (int f = 0; f < NF; f++) acc[f] = (f32x4){0.f, 0.f, 0.f, 0.f};

    const unsigned short* pa_hi = Ahi + (size_t)arow * lda + kbase;
    const unsigned short* pa_lo = Alo + (size_t)arow * lda + kbase;
    const unsigned short* pb_hi = Bph + lane * 8;
    const unsigned short* pb_lo = Bpl + lane * 8;

#pragma unroll
    for (int ks = 0; ks < K / 32; ks++) {
        bf16x8 ah = *reinterpret_cast<const bf16x8*>(pa_hi + ks * 32);
        bf16x8 al = *reinterpret_cast<const bf16x8*>(pa_lo + ks * 32);
#pragma unroll
        for (int f = 0; f < NF; f++) {
            bf16x8 bh = *reinterpret_cast<const bf16x8*>(pb_hi + (size_t)((ks * NF + f) * 64) * 8);
            bf16x8 bl = *reinterpret_cast<const bf16x8*>(pb_lo + (size_t)((ks * NF + f) * 64) * 8);
            acc[f] = __builtin_amdgcn_mfma_f32_16x16x32_bf16(ah, bh, acc[f], 0, 0, 0);
            acc[f] = __builtin_amdgcn_mfma_f32_16x16x32_bf16(ah, bl, acc[f], 0, 0, 0);
            acc[f] = __builtin_amdgcn_mfma_f32_16x16x32_bf16(al, bh, acc[f], 0, 0, 0);
        }
    }

    const int drow0 = rbase + (lane >> 4) * 4;
    const int dcol = lane & 15;
#pragma unroll
    for (int f = 0; f < NF; f++) {
#pragma unroll
        for (int r = 0; r < 4; r++) {
            int row = drow0 + r;
            if (row < NN) {
                int col = f * 16 + dcol;
                float v = acc[f][r];
                if (MODE == 0) {
                    outF[(size_t)row * ldo + col] = v * dinv[row];
                } else {
                    v = fmaxf(v + bias[col], 0.0f);
                    if (MODE == 1) {
                        unsigned short hi = f2bf(v);
                        outHi[(size_t)row * ldo + col] = hi;
                        outLo[(size_t)row * ldo + col] = f2bf(v - bf2f(hi));
                    } else {
                        outF[(size_t)row * ldo + col] = v;
                    }
                }
            }
        }
    }
}

// ---------------- layer 0: aggregate xs (3-wide, pre-scaled) per node ----------------
// ax_i = dinv_i * ( xs_i + sum_{e: dst=i} xs[src_e] )

__global__ __launch_bounds__(256) void agg_x3(
        const float* __restrict__ xs,
        const int* __restrict__ rowptr,
        const unsigned short* __restrict__ esrc16,
        const float* __restrict__ dinv,
        float* __restrict__ ax) {
    const int i = blockIdx.x * 256 + threadIdx.x;
    if (i >= NN) return;
    float a0 = xs[i * 3 + 0];
    float a1 = xs[i * 3 + 1];
    float a2 = xs[i * 3 + 2];
    const int beg = rowptr[i], end = rowptr[i + 1];
    int e = beg;
    for (; e + 3 < end; e += 4) {
        int s0 = esrc16[e], s1 = esrc16[e + 1], s2 = esrc16[e + 2], s3 = esrc16[e + 3];
        a0 += xs[s0 * 3 + 0] + xs[s1 * 3 + 0] + xs[s2 * 3 + 0] + xs[s3 * 3 + 0];
        a1 += xs[s0 * 3 + 1] + xs[s1 * 3 + 1] + xs[s2 * 3 + 1] + xs[s3 * 3 + 1];
        a2 += xs[s0 * 3 + 2] + xs[s1 * 3 + 2] + xs[s2 * 3 + 2] + xs[s3 * 3 + 2];
    }
    for (; e < end; e++) {
        int s = esrc16[e];
        a0 += xs[s * 3 + 0];
        a1 += xs[s * 3 + 1];
        a2 += xs[s * 3 + 2];
    }
    const float di = dinv[i];
    ax[i * 3 + 0] = a0 * di;
    ax[i * 3 + 1] = a1 * di;
    ax[i * 3 + 2] = a2 * di;
}

// ---------------- layer 0 dense: c0 = relu(BN(ax @ W0 + b0)), hi/lo + dup ----------------

__global__ __launch_bounds__(256) void l0_bn_relu(
        const float* __restrict__ ax, const float* __restrict__ W0,
        const float* __restrict__ b, const float* __restrict__ g,
        const float* __restrict__ beta, const float* __restrict__ rm,
        const float* __restrict__ rv,
        unsigned short* __restrict__ Hhi, unsigned short* __restrict__ Hlo) {
    const int t = blockIdx.x * 256 + threadIdx.x;
    const int row = t >> 6;
    const int ch = t & 63;
    if (row >= NN) return;
    float a0 = ax[row * 3 + 0], a1 = ax[row * 3 + 1], a2 = ax[row * 3 + 2];
    float v = a0 * W0[0 * 64 + ch] + a1 * W0[1 * 64 + ch] + a2 * W0[2 * 64 + ch] + b[ch];
    float sc = g[ch] * rsqrtf(rv[ch] + BN_EPS);
    v = (v - rm[ch]) * sc + beta[ch];
    v = fmaxf(v, 0.0f);
    unsigned short hi = f2bf(v);
    unsigned short lo = f2bf(v - bf2f(hi));
    Hhi[row * 256 + ch] = hi;
    Hlo[row * 256 + ch] = lo;
    Hhi[row * 256 + 64 + ch] = hi;
    Hlo[row * 256 + 64 + ch] = lo;
}

// ---------------- fused gather(sum of pre-scaled rows) + BN + ReLU -> hi/lo ----------------
// out = BN_ReLU( dinv[d] * (hws[d] + sum_e hws[src_e]) )

__global__ __launch_bounds__(256) void gather_bn_relu(
        const float* __restrict__ hws,
        const int* __restrict__ rowptr,
        const unsigned short* __restrict__ esrc16,
        const float* __restrict__ dinv,
        const float* __restrict__ b, const float* __restrict__ g,
        const float* __restrict__ beta, const float* __restrict__ rm,
        const float* __restrict__ rv,
        unsigned short* __restrict__ Hhi, unsigned short* __restrict__ Hlo) {
    const int wid = (blockIdx.x * 256 + threadIdx.x) >> 6;
    const int ch = threadIdx.x & 63;
    if (wid >= NN) return;
    const int beg = rowptr[wid], end = rowptr[wid + 1];
    float acc = hws[wid * 64 + ch];   // self-loop (pre-scaled)
    int e = beg;
    for (; e + 7 < end; e += 8) {
        int s0 = esrc16[e],     s1 = esrc16[e + 1], s2 = esrc16[e + 2], s3 = esrc16[e + 3];
        int s4 = esrc16[e + 4], s5 = esrc16[e + 5], s6 = esrc16[e + 6], s7 = esrc16[e + 7];
        float v0 = hws[s0 * 64 + ch], v1 = hws[s1 * 64 + ch];
        float v2 = hws[s2 * 64 + ch], v3 = hws[s3 * 64 + ch];
        float v4 = hws[s4 * 64 + ch], v5 = hws[s5 * 64 + ch];
        float v6 = hws[s6 * 64 + ch], v7 = hws[s7 * 64 + ch];
        acc += ((v0 + v1) + (v2 + v3)) + ((v4 + v5) + (v6 + v7));
    }
    for (; e < end; e++) acc += hws[esrc16[e] * 64 + ch];
    acc *= dinv[wid];
    float sc = g[ch] * rsqrtf(rv[ch] + BN_EPS);
    float v = (acc + b[ch] - rm[ch]) * sc + beta[ch];
    v = fmaxf(v, 0.0f);
    unsigned short hi = f2bf(v);
    unsigned short lo = f2bf(v - bf2f(hi));
    Hhi[wid * 256 + ch] = hi;
    Hlo[wid * 256 + ch] = lo;
}

// ---------------- per-graph mean pooling ----------------

__global__ __launch_bounds__(256) void pool_kernel(
        const float* __restrict__ e, const int* __restrict__ batch,
        float* __restrict__ gfeat_part, float* __restrict__ counts_part) {
    __shared__ float sh[4][NG][64];
    __shared__ float shc[4][NG];
    const int tid = threadIdx.x;
    const int ch = tid & 63;
    const int rg = tid >> 6;
    float acc[NG];
    float cnt[NG];
#pragma unroll
    for (int g = 0; g < NG; g++) { acc[g] = 0.0f; cnt[g] = 0.0f; }
    for (int i = blockIdx.x * 4 + rg; i < NN; i += POOL_BLOCKS * 4) {
        int b = batch[i];
        float v = e[i * 64 + ch];
#pragma unroll
        for (int g = 0; g < NG; g++) {
            acc[g] += (b == g) ? v : 0.0f;
            cnt[g] += (b == g) ? 1.0f : 0.0f;
        }
    }
#pragma unroll
    for (int g = 0; g < NG; g++) sh[rg][g][ch] = acc[g];
    if (ch == 0) {
#pragma unroll
        for (int g = 0; g < NG; g++) shc[rg][g] = cnt[g];
    }
    __syncthreads();
    const int p = blockIdx.x & (NPART - 1);
    if (rg == 0) {
#pragma unroll
        for (int g = 0; g < NG; g++) {
            float s = sh[0][g][ch] + sh[1][g][ch] + sh[2][g][ch] + sh[3][g][ch];
            atomicAdd(&gfeat_part[(p * NG + g) * 64 + ch], s);
        }
    }
    if (tid < NG) {
        float s = shc[0][tid] + shc[1][tid] + shc[2][tid] + shc[3][tid];
        atomicAdd(&counts_part[p * NG + tid], s);
    }
}

// ---------------- decoder ----------------

__global__ __launch_bounds__(256) void dec_kernel(
        const float* __restrict__ gfeat_part, const float* __restrict__ counts_part,
        const float* __restrict__ w0, const float* __restrict__ b0,
        const float* __restrict__ w1, const float* __restrict__ b1,
        float* __restrict__ out) {
    __shared__ float mg[NG][64];
    __shared__ float mc[NG];
    __shared__ float t1[NG][32];
    const int tid = threadIdx.x;
    for (int idx = tid; idx < NG * 64; idx += 256) {
        float s = 0.0f;
#pragma unroll
        for (int p = 0; p < NPART; p++) s += gfeat_part[p * NG * 64 + idx];
        mg[idx >> 6][idx & 63] = s;
    }
    if (tid < NG) {
        float s = 0.0f;
#pragma unroll
        for (int p = 0; p < NPART; p++) s += counts_part[p * NG + tid];
        mc[tid] = s;
    }
    __syncthreads();
    const int g = tid >> 5, c = tid & 31;
    float inv = 1.0f / fmaxf(mc[g], 1.0f);
    float acc = b0[c];
    for (int k = 0; k < 64; k++)
        acc = fmaf(mg[g][k] * inv, w0[k * 32 + c], acc);
    t1[g][c] = fmaxf(acc, 0.0f);
    __syncthreads();
    if (tid < NG) {
        float o = b1[0];
        for (int c2 = 0; c2 < 32; c2++) o = fmaf(t1[tid][c2], w1[c2], o);
        out[tid] = o;
    }
}

// ---------------- launch ----------------

extern "C" void kernel_launch(void* const* d_in, const int* in_sizes, int n_in,
                              void* d_out, int out_size, void* d_ws, size_t ws_size,
                              hipStream_t stream) {
    const float* x      = (const float*)d_in[0];
    const int*   ei     = (const int*)d_in[1];
    const int*   batch  = (const int*)d_in[2];
    const float* W0     = (const float*)d_in[3];
    const float* b0     = (const float*)d_in[4];
    const float* g0     = (const float*)d_in[5];
    const float* beta0  = (const float*)d_in[6];
    const float* rm0    = (const float*)d_in[7];
    const float* rv0    = (const float*)d_in[8];
    const float* W1     = (const float*)d_in[9];
    const float* b1     = (const float*)d_in[10];
    const float* g1     = (const float*)d_in[11];
    const float* beta1  = (const float*)d_in[12];
    const float* rm1    = (const float*)d_in[13];
    const float* rv1    = (const float*)d_in[14];
    const float* W2     = (const float*)d_in[15];
    const float* b2     = (const float*)d_in[16];
    const float* g2     = (const float*)d_in[17];
    const float* beta2  = (const float*)d_in[18];
    const float* rm2    = (const float*)d_in[19];
    const float* rv2    = (const float*)d_in[20];
    const float* enc_w0 = (const float*)d_in[21];
    const float* enc_b0 = (const float*)d_in[22];
    const float* enc_w1 = (const float*)d_in[23];
    const float* enc_b1 = (const float*)d_in[24];
    const float* dec_w0 = (const float*)d_in[25];
    const float* dec_b0 = (const float*)d_in[26];
    const float* dec_w1 = (const float*)d_in[27];
    const float* dec_b1 = (const float*)d_in[28];

    const int* esrc = ei;
    const int* edst = ei + NE;

    char* wsb = (char*)d_ws;
    unsigned short* Hhi = (unsigned short*)wsb;                       // [NN*256]
    unsigned short* Hlo = Hhi + (size_t)NN * 256;                     // [NN*256]
    char* U = (char*)(Hlo + (size_t)NN * 256);                        // union region
    unsigned short* Thi = (unsigned short*)U;                         // [NN*128]
    unsigned short* Tlo = Thi + (size_t)NN * 128;                     // [NN*128]
    int*   degi   = (int*)U;                                          // [NN]
    int*   rowptr = degi + NN;                                        // [NN+1]
    int*   cursor = rowptr + NN + 1;                                  // [NN]
    unsigned short* esrc16 = (unsigned short*)(cursor + NN);          // [NE] u16
    float* hws    = (float*)(U + (size_t)NN * 128 * 2 * sizeof(unsigned short));
    float* dinv   = hws + (size_t)NN * 64;
    float* xs     = dinv + NN;                                        // [NN*3]
    float* ax     = xs + (size_t)NN * 3;                              // [NN*3]
    float* gfeat_part  = ax + (size_t)NN * 3;
    float* counts_part = gfeat_part + NPART * NG * 64;
    int*   bsum   = (int*)(counts_part + NPART * NG);
    unsigned short* wp = (unsigned short*)(bsum + NBLK);
    unsigned short* Wp1h = wp;              unsigned short* Wp1l = Wp1h + 64 * 64;
    unsigned short* Wp2h = Wp1l + 64 * 64;  unsigned short* Wp2l = Wp2h + 128 * 64;
    unsigned short* We0h = Wp2l + 128 * 64; unsigned short* We0l = We0h + 256 * 128;
    unsigned short* We1h = We0l + 256 * 128;unsigned short* We1l = We1h + 128 * 64;

    hipMemsetAsync(gfeat_part, 0, (NPART * NG * 64 + NPART * NG) * sizeof(float), stream);
    hipMemsetAsync(degi, 0, NN * sizeof(int), stream);

    // CSR build
    count_deg<<<(NE + 255) / 256, 256, 0, stream>>>(edst, degi);
    compute_dinv_xs<<<NBLK, 256, 0, stream>>>(degi, x, dinv, xs);
    scan_partial<<<NBLK, 256, 0, stream>>>(degi, rowptr, bsum);
    scan_bsums<<<1, 256, 0, stream>>>(bsum);
    scan_finalize<<<NBLK, 256, 0, stream>>>(bsum, rowptr, cursor);
    fill_csr<<<(NE + 255) / 256, 256, 0, stream>>>(esrc, edst, cursor, esrc16);

    // W packs
    pack_w<<<(64 * 64 + 255) / 256, 256, 0, stream>>>(W1, 64, 64, Wp1h, Wp1l);
    pack_w<<<(128 * 64 + 255) / 256, 256, 0, stream>>>(W2, 128, 64, Wp2h, Wp2l);
    pack_w<<<(256 * 128 + 255) / 256, 256, 0, stream>>>(enc_w0, 256, 128, We0h, We0l);
    pack_w<<<(128 * 64 + 255) / 256, 256, 0, stream>>>(enc_w1, 128, 64, We1h, We1l);

    const int GRID_MFMA = (NN + 63) / 64;
    const int GRID_GATH = (NN * 64 + 255) / 256;

    // ---- layer 0: aggregate pre-scaled xs, then fused dense+BN+relu (dup write) ----
    agg_x3<<<NBLK, 256, 0, stream>>>(xs, rowptr, esrc16, dinv, ax);
    l0_bn_relu<<<GRID_GATH, 256, 0, stream>>>(ax, W0, b0, g0, beta0, rm0, rv0, Hhi, Hlo);

    // ---- layer 1: hws = dinv * (H[:,0:64] @ W1) ; gather -> cols 128-191 ----
    mfma_gemm<64, 4, 0><<<GRID_MFMA, 256, 0, stream>>>(Hhi, Hlo, 256, Wp1h, Wp1l,
                                                       nullptr, dinv, hws, nullptr, nullptr, 64);
    gather_bn_relu<<<GRID_GATH, 256, 0, stream>>>(hws, rowptr, esrc16, dinv,
                                                  b1, g1, beta1, rm1, rv1, Hhi + 128, Hlo + 128);

    // ---- layer 2: hws = dinv * (H[:,64:192] @ W2) ; gather -> cols 192-255 ----
    mfma_gemm<128, 4, 0><<<GRID_MFMA, 256, 0, stream>>>(Hhi + 64, Hlo + 64, 256, Wp2h, Wp2l,
                                                        nullptr, dinv, hws, nullptr, nullptr, 64);
    gather_bn_relu<<<GRID_GATH, 256, 0, stream>>>(hws, rowptr, esrc16, dinv,
                                                  b2, g2, beta2, rm2, rv2, Hhi + 192, Hlo + 192);

    // ---- encoder (Thi/Tlo overwrite CSR region; CSR dead from here) ----
    mfma_gemm<256, 8, 1><<<GRID_MFMA, 256, 0, stream>>>(Hhi, Hlo, 256, We0h, We0l,
                                                        enc_b0, nullptr, nullptr, Thi, Tlo, 128);
    mfma_gemm<128, 4, 2><<<GRID_MFMA, 256, 0, stream>>>(Thi, Tlo, 128, We1h, We1l,
                                                        enc_b1, nullptr, hws, nullptr, nullptr, 64);

    // ---- pool + decode ----
    pool_kernel<<<POOL_BLOCKS, 256, 0, stream>>>(hws, batch, gfeat_part, counts_part);
    dec_kernel<<<1, 256, 0, stream>>>(gfeat_part, counts_part, dec_w0, dec_b0, dec_w1, dec_b1, (float*)d_out);
}